// Round 1
// baseline (1313.946 us; speedup 1.0000x reference)
//
#include <hip/hip_runtime.h>
#include <math.h>

#define B_ 2
#define S_ 2048
#define D_ 512
#define H_ 8
#define KV_ 4
#define HD_ 64
// qkv packed row: [q(512) | k(256) | v(256)] = 1024 floats per (b,s)

// ---------------- RoPE tables (tiny, fp64 trig on fp32 argument) ----------------
__global__ void rope_table_kernel(float* __restrict__ cosT, float* __restrict__ sinT) {
    int idx = blockIdx.x * blockDim.x + threadIdx.x;
    if (idx >= S_ * (HD_ / 2)) return;
    int s = idx >> 5;
    int i = idx & 31;
    float invf = 1.0f / powf(10000.0f, (float)(2 * i) / (float)HD_);
    float arg = (float)s * invf;          // match reference fp32 argument
    double a = (double)arg;
    cosT[idx] = (float)cos(a);
    sinT[idx] = (float)sin(a);
}

// ---------------- generic Y[m][ycol0+n] = sum_k A[m][k] * W[n][k] ----------------
// A: MxK row-major (lda=K), W: NxK row-major, Y row stride ldy.
__global__ __launch_bounds__(256) void gemm_xwt(
    const float* __restrict__ A, const float* __restrict__ W, float* __restrict__ Y,
    int M, int N, int K, int ldy, int ycol0) {
    __shared__ float As[16][65];
    __shared__ float Bs[16][65];
    const int bm = blockIdx.y * 64;
    const int bn = blockIdx.x * 64;
    const int t = threadIdx.x;
    const int tr = (t >> 4) << 2;   // 0..60
    const int tc = (t & 15) << 2;   // 0..60
    const int kr = t & 15;
    const int rr = t >> 4;
    float acc[4][4] = {};
    const float* Ab = A + (size_t)bm * K;
    const float* Wb = W + (size_t)bn * K;
    for (int k0 = 0; k0 < K; k0 += 16) {
#pragma unroll
        for (int i = 0; i < 4; ++i) {
            As[kr][rr + 16 * i] = Ab[(size_t)(rr + 16 * i) * K + (k0 + kr)];
            Bs[kr][rr + 16 * i] = Wb[(size_t)(rr + 16 * i) * K + (k0 + kr)];
        }
        __syncthreads();
#pragma unroll
        for (int k = 0; k < 16; ++k) {
            float av[4], bv[4];
#pragma unroll
            for (int i = 0; i < 4; ++i) av[i] = As[k][tr + i];
#pragma unroll
            for (int j = 0; j < 4; ++j) bv[j] = Bs[k][tc + j];
#pragma unroll
            for (int i = 0; i < 4; ++i)
#pragma unroll
                for (int j = 0; j < 4; ++j) acc[i][j] += av[i] * bv[j];
        }
        __syncthreads();
    }
#pragma unroll
    for (int i = 0; i < 4; ++i)
#pragma unroll
        for (int j = 0; j < 4; ++j)
            Y[(size_t)(bm + tr + i) * ldy + (ycol0 + bn + tc + j)] = acc[i][j];
}

// ---------------- RoPE + RMSNorm in place on qkv (q heads with gain, k heads) ----------------
__global__ __launch_bounds__(256) void rope_norm_kernel(
    float* __restrict__ qkv, const float* __restrict__ cosT,
    const float* __restrict__ sinT, const float* __restrict__ gainp) {
    const int nheads = H_ + KV_;  // 12 head-vectors per (b,s)
    int gid = (blockIdx.x * blockDim.x + threadIdx.x) >> 5;  // one 32-lane group per head-vector
    int lane = threadIdx.x & 31;
    if (gid >= B_ * S_ * nheads) return;
    int hh = gid % nheads;
    int bs = gid / nheads;
    int s = bs % S_;
    float* row = qkv + (size_t)bs * 1024;
    int off = (hh < H_) ? hh * 64 : 512 + (hh - H_) * 64;
    float x1 = row[off + lane];
    float x2 = row[off + 32 + lane];
    float c = cosT[s * 32 + lane];
    float sn = sinT[s * 32 + lane];
    float y1 = x1 * c + x2 * sn;
    float y2 = x2 * c - x1 * sn;
    float ss = y1 * y1 + y2 * y2;
#pragma unroll
    for (int m = 16; m >= 1; m >>= 1) ss += __shfl_xor(ss, m, 64);
    float scale = rsqrtf(ss * (1.0f / 64.0f) + 1e-6f);
    if (hh < H_) scale *= *gainp;
    row[off + lane] = y1 * scale;
    row[off + 32 + lane] = y2 * scale;
}

// ---------------- causal flash attention, scalar fp32, 64-row q-tiles ----------------
__global__ __launch_bounds__(256) void attn_kernel(const float* __restrict__ qkv,
                                                   float* __restrict__ aout) {
    __shared__ float Qs[64][65];
    __shared__ float KVs[64][65];   // holds K tile, then V tile
    __shared__ float Ps[64][65];
    __shared__ float corr_s[64];
    __shared__ float lrow[64];

    const int nqt = S_ / 64;
    int bid = blockIdx.x;
    int qt = bid % nqt;
    int bh = bid / nqt;
    int h = bh % H_;
    int b = bh / H_;
    int kvh = h >> 1;   // rep = H/KV = 2

    const int t = threadIdx.x;
    const int lr = t >> 2;          // load row 0..63
    const int r0 = (t >> 4) << 2;   // compute rows
    const int c0 = (t & 15) << 2;   // compute cols / dims

    const float* qb = qkv + ((size_t)(b * S_ + qt * 64)) * 1024 + h * 64;
#pragma unroll
    for (int i = 0; i < 4; ++i) {
        int f4 = (t & 3) + 4 * i;
        const float4 v = *(const float4*)(qb + (size_t)lr * 1024 + f4 * 4);
        int c = f4 * 4;
        Qs[lr][c + 0] = v.x; Qs[lr][c + 1] = v.y; Qs[lr][c + 2] = v.z; Qs[lr][c + 3] = v.w;
    }

    float m_r = -INFINITY, l_r = 0.0f;
    float O[4][4] = {};
    const float* kb = qkv + (size_t)b * S_ * 1024 + 512 + kvh * 64;
    const float* vb = kb + 256;

    for (int kt = 0; kt <= qt; ++kt) {
        __syncthreads();   // prev iteration done with KVs/Ps (also covers initial Qs fill)
        // load K tile
#pragma unroll
        for (int i = 0; i < 4; ++i) {
            int f4 = (t & 3) + 4 * i;
            const float4 v = *(const float4*)(kb + (size_t)(kt * 64 + lr) * 1024 + f4 * 4);
            int c = f4 * 4;
            KVs[lr][c + 0] = v.x; KVs[lr][c + 1] = v.y; KVs[lr][c + 2] = v.z; KVs[lr][c + 3] = v.w;
        }
        __syncthreads();
        // S = Q @ K^T (4x4 microtile per thread)
        float sa[4][4] = {};
#pragma unroll
        for (int k = 0; k < 64; ++k) {
            float av[4], bv[4];
#pragma unroll
            for (int i = 0; i < 4; ++i) av[i] = Qs[r0 + i][k];
#pragma unroll
            for (int j = 0; j < 4; ++j) bv[j] = KVs[c0 + j][k];
#pragma unroll
            for (int i = 0; i < 4; ++i)
#pragma unroll
                for (int j = 0; j < 4; ++j) sa[i][j] += av[i] * bv[j];
        }
#pragma unroll
        for (int i = 0; i < 4; ++i) {
            int qg = qt * 64 + r0 + i;
#pragma unroll
            for (int j = 0; j < 4; ++j) {
                int pg = kt * 64 + c0 + j;
                Ps[r0 + i][c0 + j] = (pg <= qg) ? sa[i][j] * 0.125f : -INFINITY;
            }
        }
        __syncthreads();
        // load V tile (overwrites K) while t<64 does row softmax on Ps
#pragma unroll
        for (int i = 0; i < 4; ++i) {
            int f4 = (t & 3) + 4 * i;
            const float4 v = *(const float4*)(vb + (size_t)(kt * 64 + lr) * 1024 + f4 * 4);
            int c = f4 * 4;
            KVs[lr][c + 0] = v.x; KVs[lr][c + 1] = v.y; KVs[lr][c + 2] = v.z; KVs[lr][c + 3] = v.w;
        }
        if (t < 64) {
            float rmax = -INFINITY;
#pragma unroll 8
            for (int j = 0; j < 64; ++j) rmax = fmaxf(rmax, Ps[t][j]);
            float mnew = fmaxf(m_r, rmax);
            float corr = expf(m_r - mnew);   // first tile: exp(-inf)=0
            float lsum = 0.0f;
#pragma unroll 8
            for (int j = 0; j < 64; ++j) {
                float p = expf(Ps[t][j] - mnew);
                Ps[t][j] = p;
                lsum += p;
            }
            l_r = l_r * corr + lsum;
            m_r = mnew;
            corr_s[t] = corr;
            if (kt == qt) lrow[t] = l_r;
        }
        __syncthreads();
        // O = O*corr + P @ V
        float cf[4];
#pragma unroll
        for (int i = 0; i < 4; ++i) cf[i] = corr_s[r0 + i];
#pragma unroll
        for (int i = 0; i < 4; ++i)
#pragma unroll
            for (int j = 0; j < 4; ++j) O[i][j] *= cf[i];
#pragma unroll
        for (int p = 0; p < 64; ++p) {
            float pv[4], vv[4];
#pragma unroll
            for (int i = 0; i < 4; ++i) pv[i] = Ps[r0 + i][p];
#pragma unroll
            for (int j = 0; j < 4; ++j) vv[j] = KVs[p][c0 + j];
#pragma unroll
            for (int i = 0; i < 4; ++i)
#pragma unroll
                for (int j = 0; j < 4; ++j) O[i][j] += pv[i] * vv[j];
        }
    }
    // epilogue: divide by l, write aout[b][s][h*64+d]
    float* ob = aout + ((size_t)(b * S_ + qt * 64)) * (H_ * HD_) + h * 64;
#pragma unroll
    for (int i = 0; i < 4; ++i) {
        float linv = 1.0f / lrow[r0 + i];
#pragma unroll
        for (int j = 0; j < 4; ++j)
            ob[(size_t)(r0 + i) * (H_ * HD_) + c0 + j] = O[i][j] * linv;
    }
}

extern "C" void kernel_launch(void* const* d_in, const int* in_sizes, int n_in,
                              void* d_out, int out_size, void* d_ws, size_t ws_size,
                              hipStream_t stream) {
    const float* x    = (const float*)d_in[0];
    const float* wq   = (const float*)d_in[1];
    const float* wk   = (const float*)d_in[2];
    const float* wv   = (const float*)d_in[3];
    const float* wo   = (const float*)d_in[4];
    const float* gain = (const float*)d_in[5];
    float* out = (float*)d_out;

    float* qkv  = (float*)d_ws;                        // 4096 x 1024
    float* aout = qkv + (size_t)4096 * 1024;           // 4096 x 512
    float* cosT = aout + (size_t)4096 * 512;           // 2048 x 32
    float* sinT = cosT + (size_t)S_ * (HD_ / 2);

    rope_table_kernel<<<(S_ * (HD_ / 2) + 255) / 256, 256, 0, stream>>>(cosT, sinT);
    gemm_xwt<<<dim3(8, 64), 256, 0, stream>>>(x, wq, qkv, 4096, 512, 512, 1024, 0);
    gemm_xwt<<<dim3(4, 64), 256, 0, stream>>>(x, wk, qkv, 4096, 256, 512, 1024, 512);
    gemm_xwt<<<dim3(4, 64), 256, 0, stream>>>(x, wv, qkv, 4096, 256, 512, 1024, 768);
    rope_norm_kernel<<<(B_ * S_ * 12 * 32) / 256, 256, 0, stream>>>(qkv, cosT, sinT, gain);
    attn_kernel<<<B_ * H_ * (S_ / 64), 256, 0, stream>>>(qkv, aout);
    gemm_xwt<<<dim3(8, 64), 256, 0, stream>>>(aout, wo, out, 4096, 512, 512, 512, 0);
}

// Round 2
// 319.337 us; speedup vs baseline: 4.1146x; 4.1146x over previous
//
#include <hip/hip_runtime.h>
#include <math.h>

#define B_ 2
#define S_ 2048
#define D_ 512
#define H_ 8
#define KV_ 4
#define HD_ 64
// qkv packed row (bf16): [q(512) | k(256) | v(256)] = 1024 per (b,s)

typedef __attribute__((ext_vector_type(8))) short bf16x8;
typedef __attribute__((ext_vector_type(4))) float f32x4;

static __device__ __forceinline__ unsigned short f2bf(float f) {
    union { float f; unsigned u; } v; v.f = f;
    unsigned r = v.u + 0x7FFFu + ((v.u >> 16) & 1);
    return (unsigned short)(r >> 16);
}
static __device__ __forceinline__ float bf2f(unsigned short h) {
    union { unsigned u; float f; } v; v.u = ((unsigned)h) << 16;
    return v.f;
}

// ---------------- RoPE tables (tiny, fp64 trig on fp32 argument) ----------------
__global__ void rope_table_kernel(float* __restrict__ cosT, float* __restrict__ sinT) {
    int idx = blockIdx.x * blockDim.x + threadIdx.x;
    if (idx >= S_ * (HD_ / 2)) return;
    int s = idx >> 5;
    int i = idx & 31;
    float invf = 1.0f / powf(10000.0f, (float)(2 * i) / (float)HD_);
    float arg = (float)s * invf;
    double a = (double)arg;
    cosT[idx] = (float)cos(a);
    sinT[idx] = (float)sin(a);
}

// ---------------- Y[m][ycol0+n] = sum_k A[m][k]*W[n][k], OutT = float|bf16 ----------------
template <typename OutT>
__global__ __launch_bounds__(256) void gemm_xwt(
    const float* __restrict__ A, const float* __restrict__ W, OutT* __restrict__ Y,
    int M, int N, int K, int ldy, int ycol0) {
    __shared__ float As[16][65];
    __shared__ float Bs[16][65];
    const int bm = blockIdx.y * 64;
    const int bn = blockIdx.x * 64;
    const int t = threadIdx.x;
    const int tr = (t >> 4) << 2;
    const int tc = (t & 15) << 2;
    const int kr = t & 15;
    const int rr = t >> 4;
    float acc[4][4] = {};
    const float* Ab = A + (size_t)bm * K;
    const float* Wb = W + (size_t)bn * K;
    for (int k0 = 0; k0 < K; k0 += 16) {
#pragma unroll
        for (int i = 0; i < 4; ++i) {
            As[kr][rr + 16 * i] = Ab[(size_t)(rr + 16 * i) * K + (k0 + kr)];
            Bs[kr][rr + 16 * i] = Wb[(size_t)(rr + 16 * i) * K + (k0 + kr)];
        }
        __syncthreads();
#pragma unroll
        for (int k = 0; k < 16; ++k) {
            float av[4], bv[4];
#pragma unroll
            for (int i = 0; i < 4; ++i) av[i] = As[k][tr + i];
#pragma unroll
            for (int j = 0; j < 4; ++j) bv[j] = Bs[k][tc + j];
#pragma unroll
            for (int i = 0; i < 4; ++i)
#pragma unroll
                for (int j = 0; j < 4; ++j) acc[i][j] += av[i] * bv[j];
        }
        __syncthreads();
    }
#pragma unroll
    for (int i = 0; i < 4; ++i)
#pragma unroll
        for (int j = 0; j < 4; ++j) {
            float v = acc[i][j];
            if constexpr (sizeof(OutT) == 2)
                Y[(size_t)(bm + tr + i) * ldy + (ycol0 + bn + tc + j)] = (OutT)f2bf(v);
            else
                Y[(size_t)(bm + tr + i) * ldy + (ycol0 + bn + tc + j)] = (OutT)v;
        }
}

// ---------------- RoPE + RMSNorm in place on bf16 qkv ----------------
__global__ __launch_bounds__(256) void rope_norm_kernel(
    unsigned short* __restrict__ qkv, const float* __restrict__ cosT,
    const float* __restrict__ sinT, const float* __restrict__ gainp) {
    const int nheads = H_ + KV_;
    int gid = (blockIdx.x * blockDim.x + threadIdx.x) >> 5;
    int lane = threadIdx.x & 31;
    if (gid >= B_ * S_ * nheads) return;
    int hh = gid % nheads;
    int bs = gid / nheads;
    int s = bs % S_;
    unsigned short* row = qkv + (size_t)bs * 1024;
    int off = (hh < H_) ? hh * 64 : 512 + (hh - H_) * 64;
    float x1 = bf2f(row[off + lane]);
    float x2 = bf2f(row[off + 32 + lane]);
    float c = cosT[s * 32 + lane];
    float sn = sinT[s * 32 + lane];
    float y1 = x1 * c + x2 * sn;
    float y2 = x2 * c - x1 * sn;
    float ss = y1 * y1 + y2 * y2;
#pragma unroll
    for (int m = 16; m >= 1; m >>= 1) ss += __shfl_xor(ss, m, 64);
    float scale = rsqrtf(ss * (1.0f / 64.0f) + 1e-6f);
    if (hh < H_) scale *= *gainp;
    row[off + lane] = f2bf(y1 * scale);
    row[off + 32 + lane] = f2bf(y2 * scale);
}

// ---------------- MFMA flash attention: block = (b,h,64-row q tile), 4 waves ----------------
// Swizzle: byte = row*128 + (colByte ^ (((row + (row>>3)) & 7) << 4))
#define SWZF(row) ((((row) + ((row) >> 3)) & 7) << 4)

__global__ __launch_bounds__(256) void attn_mfma(const unsigned short* __restrict__ qkv,
                                                 float* __restrict__ aout) {
    __shared__ short Qs[64 * 64];
    __shared__ short Ks[64 * 64];
    __shared__ short Vts[64 * 64];   // transposed: [d][key]
    __shared__ short Ps[64 * 64];

    const int nqt = S_ / 64;
    const int bid = blockIdx.x;
    const int bh = bid & 15;
    const int qt = (nqt - 1) - (bid >> 4);   // long blocks first
    const int h = bh & 7;
    const int b = bh >> 3;
    const int kvh = h >> 1;

    const int t = threadIdx.x;
    const int w = t >> 6;    // wave id: q rows [w*16, w*16+16)
    const int l = t & 63;
    const int g = l >> 4;    // k-group
    const int c = l & 15;    // col-in-tile

    // ---- stage Q (64 x 64 bf16) ----
    const unsigned short* qsrc = qkv + ((size_t)(b * S_ + qt * 64)) * 1024 + h * 64;
#pragma unroll
    for (int cc = t; cc < 512; cc += 256) {
        int row = cc >> 3, seg = cc & 7;
        bf16x8 v = *(const bf16x8*)(qsrc + (size_t)row * 1024 + seg * 8);
        *(bf16x8*)((char*)Qs + row * 128 + ((seg * 16) ^ SWZF(row))) = v;
    }
    __syncthreads();

    // ---- Q fragments (A layout: row = lane&15, k = (lane>>4)*8 + i) ----
    bf16x8 aq0, aq1;
    {
        int row = w * 16 + c;
        int fx = SWZF(row);
        aq0 = *(const bf16x8*)((const char*)Qs + row * 128 + ((g * 16) ^ fx));
        aq1 = *(const bf16x8*)((const char*)Qs + row * 128 + ((64 + g * 16) ^ fx));
    }

    float m_r[4], l_r[4];
    f32x4 o_acc[4] = {};
#pragma unroll
    for (int r = 0; r < 4; ++r) { m_r[r] = -INFINITY; l_r[r] = 0.0f; }

    const unsigned short* ksrc0 = qkv + ((size_t)(b * S_)) * 1024 + 512 + kvh * 64;
    const unsigned short* vsrc0 = ksrc0 + 256;

    for (int kt = 0; kt <= qt; ++kt) {
        // ---- stage K tile + transposed V tile ----
        const unsigned short* ks = ksrc0 + (size_t)kt * 64 * 1024;
        const unsigned short* vs = vsrc0 + (size_t)kt * 64 * 1024;
#pragma unroll
        for (int cc = t; cc < 512; cc += 256) {
            int row = cc >> 3, seg = cc & 7;
            bf16x8 kv = *(const bf16x8*)(ks + (size_t)row * 1024 + seg * 8);
            *(bf16x8*)((char*)Ks + row * 128 + ((seg * 16) ^ SWZF(row))) = kv;
            bf16x8 vv = *(const bf16x8*)(vs + (size_t)row * 1024 + seg * 8);
#pragma unroll
            for (int i = 0; i < 8; ++i) {
                int d = seg * 8 + i;                      // SWZF(d) = ((i+seg)&7)<<4
                *(short*)((char*)Vts + d * 128 + ((row * 2) ^ SWZF(d))) = vv[i];
            }
        }
        __syncthreads();

        // ---- S = Q K^T : per wave 16x64, C layout col(key)=lane&15, row(q)=g*4+r ----
        f32x4 sA[4];
#pragma unroll
        for (int nt = 0; nt < 4; ++nt) {
            int krow = nt * 16 + c;
            int fk = SWZF(krow);
            bf16x8 b0 = *(const bf16x8*)((const char*)Ks + krow * 128 + ((g * 16) ^ fk));
            bf16x8 b1 = *(const bf16x8*)((const char*)Ks + krow * 128 + ((64 + g * 16) ^ fk));
            f32x4 acc = {0.f, 0.f, 0.f, 0.f};
            acc = __builtin_amdgcn_mfma_f32_16x16x32_bf16(aq0, b0, acc, 0, 0, 0);
            acc = __builtin_amdgcn_mfma_f32_16x16x32_bf16(aq1, b1, acc, 0, 0, 0);
            sA[nt] = acc;
        }
        // ---- scale + causal mask ----
#pragma unroll
        for (int nt = 0; nt < 4; ++nt) {
            int key = kt * 64 + nt * 16 + c;
#pragma unroll
            for (int r = 0; r < 4; ++r) {
                int qrow = qt * 64 + w * 16 + g * 4 + r;
                float sc = sA[nt][r] * 0.125f;
                sA[nt][r] = (key <= qrow) ? sc : -1e30f;
            }
        }
        // ---- online softmax (wave-parallel; reduce over 16 key-lanes) ----
        const float L2E = 1.4426950408889634f;
        float mnew[4], corr[4], lsum[4];
#pragma unroll
        for (int r = 0; r < 4; ++r) {
            float mx = fmaxf(fmaxf(sA[0][r], sA[1][r]), fmaxf(sA[2][r], sA[3][r]));
            mx = fmaxf(mx, __shfl_xor(mx, 1, 64));
            mx = fmaxf(mx, __shfl_xor(mx, 2, 64));
            mx = fmaxf(mx, __shfl_xor(mx, 4, 64));
            mx = fmaxf(mx, __shfl_xor(mx, 8, 64));
            mnew[r] = fmaxf(m_r[r], mx);
            corr[r] = exp2f((m_r[r] - mnew[r]) * L2E);
            m_r[r] = mnew[r];
            lsum[r] = 0.0f;
        }
#pragma unroll
        for (int nt = 0; nt < 4; ++nt) {
#pragma unroll
            for (int r = 0; r < 4; ++r) {
                float p = exp2f((sA[nt][r] - mnew[r]) * L2E);
                unsigned short pb = f2bf(p);
                lsum[r] += bf2f(pb);       // denominator matches rounded numerator
                int qrow = w * 16 + g * 4 + r;
                int key = nt * 16 + c;
                *(short*)((char*)Ps + qrow * 128 + ((key * 2) ^ SWZF(qrow))) = (short)pb;
            }
        }
#pragma unroll
        for (int r = 0; r < 4; ++r) {
            float ls = lsum[r];
            ls += __shfl_xor(ls, 1, 64);
            ls += __shfl_xor(ls, 2, 64);
            ls += __shfl_xor(ls, 4, 64);
            ls += __shfl_xor(ls, 8, 64);
            l_r[r] = l_r[r] * corr[r] + ls;
            o_acc[0][r] *= corr[r];
            o_acc[1][r] *= corr[r];
            o_acc[2][r] *= corr[r];
            o_acc[3][r] *= corr[r];
        }
        // ---- O += P V  (A = P from own strip; B = V via transposed tile) ----
        {
            int prow = w * 16 + c;
            int fp = SWZF(prow);
            bf16x8 pa0 = *(const bf16x8*)((const char*)Ps + prow * 128 + ((g * 16) ^ fp));
            bf16x8 pa1 = *(const bf16x8*)((const char*)Ps + prow * 128 + ((64 + g * 16) ^ fp));
#pragma unroll
            for (int nt = 0; nt < 4; ++nt) {
                int drow = nt * 16 + c;
                int fv = SWZF(drow);
                bf16x8 vb0 = *(const bf16x8*)((const char*)Vts + drow * 128 + ((g * 16) ^ fv));
                bf16x8 vb1 = *(const bf16x8*)((const char*)Vts + drow * 128 + ((64 + g * 16) ^ fv));
                o_acc[nt] = __builtin_amdgcn_mfma_f32_16x16x32_bf16(pa0, vb0, o_acc[nt], 0, 0, 0);
                o_acc[nt] = __builtin_amdgcn_mfma_f32_16x16x32_bf16(pa1, vb1, o_acc[nt], 0, 0, 0);
            }
        }
        __syncthreads();   // protect Ks/Vts before next-iter restaging
    }

    // ---- epilogue: O /= l, write fp32 aout[b][s][h*64+d] ----
    float* ob = aout + ((size_t)(b * S_ + qt * 64 + w * 16)) * (H_ * HD_) + h * 64;
#pragma unroll
    for (int r = 0; r < 4; ++r) {
        float inv = 1.0f / l_r[r];
#pragma unroll
        for (int nt = 0; nt < 4; ++nt)
            ob[(size_t)(g * 4 + r) * (H_ * HD_) + nt * 16 + c] = o_acc[nt][r] * inv;
    }
}

extern "C" void kernel_launch(void* const* d_in, const int* in_sizes, int n_in,
                              void* d_out, int out_size, void* d_ws, size_t ws_size,
                              hipStream_t stream) {
    const float* x    = (const float*)d_in[0];
    const float* wq   = (const float*)d_in[1];
    const float* wk   = (const float*)d_in[2];
    const float* wv   = (const float*)d_in[3];
    const float* wo   = (const float*)d_in[4];
    const float* gain = (const float*)d_in[5];
    float* out = (float*)d_out;

    unsigned short* qkv = (unsigned short*)d_ws;                         // 4096x1024 bf16 (8 MB)
    float* aout = (float*)((char*)d_ws + (size_t)8 * 1024 * 1024);       // 4096x512 fp32 (8 MB)
    float* cosT = aout + (size_t)4096 * 512;
    float* sinT = cosT + (size_t)S_ * (HD_ / 2);

    rope_table_kernel<<<(S_ * (HD_ / 2) + 255) / 256, 256, 0, stream>>>(cosT, sinT);
    gemm_xwt<unsigned short><<<dim3(8, 64), 256, 0, stream>>>(x, wq, qkv, 4096, 512, 512, 1024, 0);
    gemm_xwt<unsigned short><<<dim3(4, 64), 256, 0, stream>>>(x, wk, qkv, 4096, 256, 512, 1024, 512);
    gemm_xwt<unsigned short><<<dim3(4, 64), 256, 0, stream>>>(x, wv, qkv, 4096, 256, 512, 1024, 768);
    rope_norm_kernel<<<(B_ * S_ * 12 * 32) / 256, 256, 0, stream>>>(qkv, cosT, sinT, gain);
    attn_mfma<<<16 * (S_ / 64), 256, 0, stream>>>(qkv, aout);
    gemm_xwt<float><<<dim3(8, 64), 256, 0, stream>>>(aout, wo, out, 4096, 512, 512, 512, 0);
}

// Round 3
// 125.876 us; speedup vs baseline: 10.4384x; 2.5369x over previous
//
#include <hip/hip_runtime.h>
#include <math.h>

#define B_ 2
#define S_ 2048
#define D_ 512
#define H_ 8
#define KV_ 4
#define HD_ 64
// qkv packed row (bf16): [q(512) | k(256) | v(256)] = 1024 per (b,s)

typedef __attribute__((ext_vector_type(8))) short bf16x8;
typedef __attribute__((ext_vector_type(4))) short bf16x4;
typedef __attribute__((ext_vector_type(4))) float f32x4;

static __device__ __forceinline__ unsigned short f2bf(float f) {
    union { float f; unsigned u; } v; v.f = f;
    unsigned r = v.u + 0x7FFFu + ((v.u >> 16) & 1);
    return (unsigned short)(r >> 16);
}
static __device__ __forceinline__ float bf2f(unsigned short h) {
    union { unsigned u; float f; } v; v.u = ((unsigned)h) << 16;
    return v.f;
}

// ---------------- RoPE tables (tiny, fp64 trig on fp32 argument) ----------------
__global__ void rope_table_kernel(float* __restrict__ cosT, float* __restrict__ sinT) {
    int idx = blockIdx.x * blockDim.x + threadIdx.x;
    if (idx >= S_ * (HD_ / 2)) return;
    int s = idx >> 5;
    int i = idx & 31;
    float invf = 1.0f / powf(10000.0f, (float)(2 * i) / (float)HD_);
    float arg = (float)s * invf;
    double a = (double)arg;
    cosT[idx] = (float)cos(a);
    sinT[idx] = (float)sin(a);
}

// ---------------- fp32 -> bf16 conversion/packing (x, wq|wk|wv fused, wo) ----------------
// element regions: [0,2097152) x ; then wq 262144 ; wk 131072 ; wv 131072 ; wo 262144
__global__ __launch_bounds__(256) void convert_pack_kernel(
    const float* __restrict__ x, const float* __restrict__ wq, const float* __restrict__ wk,
    const float* __restrict__ wv, const float* __restrict__ wo,
    unsigned short* __restrict__ xb, unsigned short* __restrict__ wqkv_b,
    unsigned short* __restrict__ wo_b) {
    int i4 = blockIdx.x * blockDim.x + threadIdx.x;
    int e = i4 * 4;
    const float* src;
    unsigned short* dst;
    if (e < 2097152)      { src = x + e;               dst = xb + e; }
    else if (e < 2359296) { src = wq + (e - 2097152);  dst = wqkv_b + (e - 2097152); }
    else if (e < 2490368) { src = wk + (e - 2359296);  dst = wqkv_b + (e - 2097152); }
    else if (e < 2621440) { src = wv + (e - 2490368);  dst = wqkv_b + (e - 2097152); }
    else                  { src = wo + (e - 2621440);  dst = wo_b + (e - 2621440); }
    float4 v = *(const float4*)src;
    bf16x4 o;
    o[0] = (short)f2bf(v.x); o[1] = (short)f2bf(v.y);
    o[2] = (short)f2bf(v.z); o[3] = (short)f2bf(v.w);
    *(bf16x4*)dst = o;
}

// ---------------- bf16 MFMA GEMM: Y[m][ycol0+n] = sum_k A[m][k]*Bw[n][k] ----------------
// 128x128 tile, BK=32, 4 waves (2x2), global_load_lds width-16 staging.
template <typename OutT>
__global__ __launch_bounds__(256) void gemm_mfma(
    const unsigned short* __restrict__ A,   // [M][K] bf16
    const unsigned short* __restrict__ Bw,  // [N][K] bf16
    OutT* __restrict__ Y, int K, int ldy, int ycol0) {
    __shared__ unsigned short As[128 * 32];
    __shared__ unsigned short Bs[128 * 32];
    const int bn = blockIdx.x * 128;
    const int bm = blockIdx.y * 128;
    const int t = threadIdx.x;
    const int w = t >> 6, l = t & 63;
    const int g = l >> 4, c = l & 15;
    const int wr = w >> 1, wc = w & 1;

    f32x4 acc[4][4] = {};

    const int lrow = l >> 2;        // row within 16-row chunk
    const int lcol = (l & 3) * 8;   // bf16 col within 32-col tile

    for (int k0 = 0; k0 < K; k0 += 32) {
#pragma unroll
        for (int r = 0; r < 2; ++r) {
            int ci = w * 2 + r;   // wave-uniform chunk id 0..7
            const unsigned short* ga = A + (size_t)(bm + ci * 16 + lrow) * K + k0 + lcol;
            __builtin_amdgcn_global_load_lds(
                (const __attribute__((address_space(1))) void*)ga,
                (__attribute__((address_space(3))) void*)(As + ci * 512), 16, 0, 0);
            const unsigned short* gb = Bw + (size_t)(bn + ci * 16 + lrow) * K + k0 + lcol;
            __builtin_amdgcn_global_load_lds(
                (const __attribute__((address_space(1))) void*)gb,
                (__attribute__((address_space(3))) void*)(Bs + ci * 512), 16, 0, 0);
        }
        __syncthreads();   // drains vmcnt (compiler emits s_waitcnt vmcnt(0) before s_barrier)
        bf16x8 av[4], bv[4];
#pragma unroll
        for (int i = 0; i < 4; ++i)
            av[i] = *(const bf16x8*)(As + (wr * 64 + i * 16 + c) * 32 + g * 8);
#pragma unroll
        for (int j = 0; j < 4; ++j)
            bv[j] = *(const bf16x8*)(Bs + (wc * 64 + j * 16 + c) * 32 + g * 8);
#pragma unroll
        for (int i = 0; i < 4; ++i)
#pragma unroll
            for (int j = 0; j < 4; ++j)
                acc[i][j] = __builtin_amdgcn_mfma_f32_16x16x32_bf16(av[i], bv[j], acc[i][j], 0, 0, 0);
        __syncthreads();
    }
#pragma unroll
    for (int i = 0; i < 4; ++i)
#pragma unroll
        for (int j = 0; j < 4; ++j)
#pragma unroll
            for (int r = 0; r < 4; ++r) {
                int row = bm + wr * 64 + i * 16 + g * 4 + r;
                int col = ycol0 + bn + wc * 64 + j * 16 + c;
                float v = acc[i][j][r];
                if constexpr (sizeof(OutT) == 2)
                    Y[(size_t)row * ldy + col] = (OutT)f2bf(v);
                else
                    Y[(size_t)row * ldy + col] = v;
            }
}

// ---------------- RoPE + RMSNorm in place on bf16 qkv ----------------
__global__ __launch_bounds__(256) void rope_norm_kernel(
    unsigned short* __restrict__ qkv, const float* __restrict__ cosT,
    const float* __restrict__ sinT, const float* __restrict__ gainp) {
    const int nheads = H_ + KV_;
    int gid = (blockIdx.x * blockDim.x + threadIdx.x) >> 5;
    int lane = threadIdx.x & 31;
    if (gid >= B_ * S_ * nheads) return;
    int hh = gid % nheads;
    int bs = gid / nheads;
    int s = bs % S_;
    unsigned short* row = qkv + (size_t)bs * 1024;
    int off = (hh < H_) ? hh * 64 : 512 + (hh - H_) * 64;
    float x1 = bf2f(row[off + lane]);
    float x2 = bf2f(row[off + 32 + lane]);
    float c = cosT[s * 32 + lane];
    float sn = sinT[s * 32 + lane];
    float y1 = x1 * c + x2 * sn;
    float y2 = x2 * c - x1 * sn;
    float ss = y1 * y1 + y2 * y2;
#pragma unroll
    for (int m = 16; m >= 1; m >>= 1) ss += __shfl_xor(ss, m, 64);
    float scale = rsqrtf(ss * (1.0f / 64.0f) + 1e-6f);
    if (hh < H_) scale *= *gainp;
    row[off + lane] = f2bf(y1 * scale);
    row[off + 32 + lane] = f2bf(y2 * scale);
}

// ---------------- MFMA flash attention: block = (b,h,64-row q tile), 4 waves ----------------
#define SWZF(row) ((((row) + ((row) >> 3)) & 7) << 4)

__global__ __launch_bounds__(256) void attn_mfma(const unsigned short* __restrict__ qkv,
                                                 unsigned short* __restrict__ aout) {
    __shared__ short Qs[64 * 64];
    __shared__ short Ks[64 * 64];
    __shared__ short Vts[64 * 64];   // transposed: [d][key]
    __shared__ short Ps[64 * 64];

    const int nqt = S_ / 64;
    const int bid = blockIdx.x;
    const int bh = bid & 15;
    const int qt = (nqt - 1) - (bid >> 4);   // long blocks first
    const int h = bh & 7;
    const int b = bh >> 3;
    const int kvh = h >> 1;

    const int t = threadIdx.x;
    const int w = t >> 6;
    const int l = t & 63;
    const int g = l >> 4;
    const int c = l & 15;

    const unsigned short* qsrc = qkv + ((size_t)(b * S_ + qt * 64)) * 1024 + h * 64;
#pragma unroll
    for (int cc = t; cc < 512; cc += 256) {
        int row = cc >> 3, seg = cc & 7;
        bf16x8 v = *(const bf16x8*)(qsrc + (size_t)row * 1024 + seg * 8);
        *(bf16x8*)((char*)Qs + row * 128 + ((seg * 16) ^ SWZF(row))) = v;
    }
    __syncthreads();

    bf16x8 aq0, aq1;
    {
        int row = w * 16 + c;
        int fx = SWZF(row);
        aq0 = *(const bf16x8*)((const char*)Qs + row * 128 + ((g * 16) ^ fx));
        aq1 = *(const bf16x8*)((const char*)Qs + row * 128 + ((64 + g * 16) ^ fx));
    }

    float m_r[4], l_r[4];
    f32x4 o_acc[4] = {};
#pragma unroll
    for (int r = 0; r < 4; ++r) { m_r[r] = -INFINITY; l_r[r] = 0.0f; }

    const unsigned short* ksrc0 = qkv + ((size_t)(b * S_)) * 1024 + 512 + kvh * 64;
    const unsigned short* vsrc0 = ksrc0 + 256;

    for (int kt = 0; kt <= qt; ++kt) {
        const unsigned short* ks = ksrc0 + (size_t)kt * 64 * 1024;
        const unsigned short* vs = vsrc0 + (size_t)kt * 64 * 1024;
#pragma unroll
        for (int cc = t; cc < 512; cc += 256) {
            int row = cc >> 3, seg = cc & 7;
            bf16x8 kv = *(const bf16x8*)(ks + (size_t)row * 1024 + seg * 8);
            *(bf16x8*)((char*)Ks + row * 128 + ((seg * 16) ^ SWZF(row))) = kv;
            bf16x8 vv = *(const bf16x8*)(vs + (size_t)row * 1024 + seg * 8);
#pragma unroll
            for (int i = 0; i < 8; ++i) {
                int d = seg * 8 + i;
                *(short*)((char*)Vts + d * 128 + ((row * 2) ^ SWZF(d))) = vv[i];
            }
        }
        __syncthreads();

        f32x4 sA[4];
#pragma unroll
        for (int nt = 0; nt < 4; ++nt) {
            int krow = nt * 16 + c;
            int fk = SWZF(krow);
            bf16x8 b0 = *(const bf16x8*)((const char*)Ks + krow * 128 + ((g * 16) ^ fk));
            bf16x8 b1 = *(const bf16x8*)((const char*)Ks + krow * 128 + ((64 + g * 16) ^ fk));
            f32x4 acc = {0.f, 0.f, 0.f, 0.f};
            acc = __builtin_amdgcn_mfma_f32_16x16x32_bf16(aq0, b0, acc, 0, 0, 0);
            acc = __builtin_amdgcn_mfma_f32_16x16x32_bf16(aq1, b1, acc, 0, 0, 0);
            sA[nt] = acc;
        }
#pragma unroll
        for (int nt = 0; nt < 4; ++nt) {
            int key = kt * 64 + nt * 16 + c;
#pragma unroll
            for (int r = 0; r < 4; ++r) {
                int qrow = qt * 64 + w * 16 + g * 4 + r;
                float sc = sA[nt][r] * 0.125f;
                sA[nt][r] = (key <= qrow) ? sc : -1e30f;
            }
        }
        const float L2E = 1.4426950408889634f;
        float mnew[4], corr[4], lsum[4];
#pragma unroll
        for (int r = 0; r < 4; ++r) {
            float mx = fmaxf(fmaxf(sA[0][r], sA[1][r]), fmaxf(sA[2][r], sA[3][r]));
            mx = fmaxf(mx, __shfl_xor(mx, 1, 64));
            mx = fmaxf(mx, __shfl_xor(mx, 2, 64));
            mx = fmaxf(mx, __shfl_xor(mx, 4, 64));
            mx = fmaxf(mx, __shfl_xor(mx, 8, 64));
            mnew[r] = fmaxf(m_r[r], mx);
            corr[r] = exp2f((m_r[r] - mnew[r]) * L2E);
            m_r[r] = mnew[r];
            lsum[r] = 0.0f;
        }
#pragma unroll
        for (int nt = 0; nt < 4; ++nt) {
#pragma unroll
            for (int r = 0; r < 4; ++r) {
                float p = exp2f((sA[nt][r] - mnew[r]) * L2E);
                unsigned short pb = f2bf(p);
                lsum[r] += bf2f(pb);
                int qrow = w * 16 + g * 4 + r;
                int key = nt * 16 + c;
                *(short*)((char*)Ps + qrow * 128 + ((key * 2) ^ SWZF(qrow))) = (short)pb;
            }
        }
#pragma unroll
        for (int r = 0; r < 4; ++r) {
            float ls = lsum[r];
            ls += __shfl_xor(ls, 1, 64);
            ls += __shfl_xor(ls, 2, 64);
            ls += __shfl_xor(ls, 4, 64);
            ls += __shfl_xor(ls, 8, 64);
            l_r[r] = l_r[r] * corr[r] + ls;
            o_acc[0][r] *= corr[r];
            o_acc[1][r] *= corr[r];
            o_acc[2][r] *= corr[r];
            o_acc[3][r] *= corr[r];
        }
        {
            int prow = w * 16 + c;
            int fp = SWZF(prow);
            bf16x8 pa0 = *(const bf16x8*)((const char*)Ps + prow * 128 + ((g * 16) ^ fp));
            bf16x8 pa1 = *(const bf16x8*)((const char*)Ps + prow * 128 + ((64 + g * 16) ^ fp));
#pragma unroll
            for (int nt = 0; nt < 4; ++nt) {
                int drow = nt * 16 + c;
                int fv = SWZF(drow);
                bf16x8 vb0 = *(const bf16x8*)((const char*)Vts + drow * 128 + ((g * 16) ^ fv));
                bf16x8 vb1 = *(const bf16x8*)((const char*)Vts + drow * 128 + ((64 + g * 16) ^ fv));
                o_acc[nt] = __builtin_amdgcn_mfma_f32_16x16x32_bf16(pa0, vb0, o_acc[nt], 0, 0, 0);
                o_acc[nt] = __builtin_amdgcn_mfma_f32_16x16x32_bf16(pa1, vb1, o_acc[nt], 0, 0, 0);
            }
        }
        __syncthreads();
    }

    // epilogue: O /= l, write bf16 aout[b][s][h*64+d]
    unsigned short* ob = aout + ((size_t)(b * S_ + qt * 64 + w * 16)) * (H_ * HD_) + h * 64;
#pragma unroll
    for (int r = 0; r < 4; ++r) {
        float inv = 1.0f / l_r[r];
#pragma unroll
        for (int nt = 0; nt < 4; ++nt)
            ob[(size_t)(g * 4 + r) * (H_ * HD_) + nt * 16 + c] = f2bf(o_acc[nt][r] * inv);
    }
}

extern "C" void kernel_launch(void* const* d_in, const int* in_sizes, int n_in,
                              void* d_out, int out_size, void* d_ws, size_t ws_size,
                              hipStream_t stream) {
    const float* x    = (const float*)d_in[0];
    const float* wq   = (const float*)d_in[1];
    const float* wk   = (const float*)d_in[2];
    const float* wv   = (const float*)d_in[3];
    const float* wo   = (const float*)d_in[4];
    const float* gain = (const float*)d_in[5];
    float* out = (float*)d_out;

    char* ws = (char*)d_ws;
    unsigned short* qkv    = (unsigned short*)(ws);                          // 8 MB: 4096x1024 bf16
    unsigned short* aout   = (unsigned short*)(ws + (size_t)8  * 1024 * 1024); // 4 MB: 4096x512 bf16
    unsigned short* xb     = (unsigned short*)(ws + (size_t)12 * 1024 * 1024); // 4 MB: 4096x512 bf16
    unsigned short* wqkv_b = (unsigned short*)(ws + (size_t)16 * 1024 * 1024); // 1 MB: 1024x512 bf16
    unsigned short* wo_b   = (unsigned short*)(ws + (size_t)17 * 1024 * 1024); // 0.5 MB: 512x512 bf16
    float* cosT            = (float*)(ws + (size_t)18 * 1024 * 1024);          // 256 KB
    float* sinT            = cosT + (size_t)S_ * (HD_ / 2);

    rope_table_kernel<<<(S_ * (HD_ / 2) + 255) / 256, 256, 0, stream>>>(cosT, sinT);
    convert_pack_kernel<<<(2883584 / 4) / 256, 256, 0, stream>>>(x, wq, wk, wv, wo,
                                                                 xb, wqkv_b, wo_b);
    gemm_mfma<unsigned short><<<dim3(8, 32), 256, 0, stream>>>(xb, wqkv_b, qkv, 512, 1024, 0);
    rope_norm_kernel<<<(B_ * S_ * 12 * 32) / 256, 256, 0, stream>>>(qkv, cosT, sinT, gain);
    attn_mfma<<<16 * (S_ / 64), 256, 0, stream>>>(qkv, aout);
    gemm_mfma<float><<<dim3(4, 32), 256, 0, stream>>>(aout, wo_b, out, 512, 512, 0);
}

// Round 4
// 98.589 us; speedup vs baseline: 13.3275x; 1.2768x over previous
//
#include <hip/hip_runtime.h>
#include <math.h>

#define B_ 2
#define S_ 2048
#define D_ 512
#define H_ 8
#define KV_ 4
#define HD_ 64
// qkv row (bf16, stride 768): [q(512) | k(256)] ; V lives transposed in vt[256][4096]

typedef __attribute__((ext_vector_type(8))) short bf16x8;
typedef __attribute__((ext_vector_type(4))) short bf16x4;
typedef __attribute__((ext_vector_type(4))) float f32x4;

static __device__ __forceinline__ unsigned short f2bf(float f) {
    union { float f; unsigned u; } v; v.f = f;
    unsigned r = v.u + 0x7FFFu + ((v.u >> 16) & 1);
    return (unsigned short)(r >> 16);
}

// ---------------- RoPE tables ----------------
__global__ void rope_table_kernel(float* __restrict__ cosT, float* __restrict__ sinT) {
    int idx = blockIdx.x * blockDim.x + threadIdx.x;
    if (idx >= S_ * (HD_ / 2)) return;
    int s = idx >> 5;
    int i = idx & 31;
    float invf = 1.0f / powf(10000.0f, (float)(2 * i) / (float)HD_);
    float arg = (float)s * invf;
    double a = (double)arg;
    cosT[idx] = (float)cos(a);
    sinT[idx] = (float)sin(a);
}

// ---------------- fp32 -> bf16 pack: x ; wq|wk|wv fused ; wo ----------------
__global__ __launch_bounds__(256) void convert_pack_kernel(
    const float* __restrict__ x, const float* __restrict__ wq, const float* __restrict__ wk,
    const float* __restrict__ wv, const float* __restrict__ wo,
    unsigned short* __restrict__ xb, unsigned short* __restrict__ wqkv_b,
    unsigned short* __restrict__ wo_b) {
    int i4 = blockIdx.x * blockDim.x + threadIdx.x;
    int e = i4 * 4;
    const float* src;
    unsigned short* dst;
    if (e < 2097152)      { src = x + e;               dst = xb + e; }
    else if (e < 2359296) { src = wq + (e - 2097152);  dst = wqkv_b + (e - 2097152); }
    else if (e < 2490368) { src = wk + (e - 2359296);  dst = wqkv_b + (e - 2097152); }
    else if (e < 2621440) { src = wv + (e - 2490368);  dst = wqkv_b + (e - 2097152); }
    else                  { src = wo + (e - 2621440);  dst = wo_b + (e - 2621440); }
    float4 v = *(const float4*)src;
    bf16x4 o;
    o[0] = (short)f2bf(v.x); o[1] = (short)f2bf(v.y);
    o[2] = (short)f2bf(v.z); o[3] = (short)f2bf(v.w);
    *(bf16x4*)dst = o;
}

// ---------------- bf16 MFMA GEMM: Y[m][n] = sum_k A[m][k]*Bw[n][k] ----------------
template <typename OutT>
__global__ __launch_bounds__(256) void gemm_mfma(
    const unsigned short* __restrict__ A, const unsigned short* __restrict__ Bw,
    OutT* __restrict__ Y, int K, int ldy) {
    __shared__ unsigned short As[128 * 32];
    __shared__ unsigned short Bs[128 * 32];
    const int bn = blockIdx.x * 128;
    const int bm = blockIdx.y * 128;
    const int t = threadIdx.x;
    const int w = t >> 6, l = t & 63;
    const int g = l >> 4, c = l & 15;
    const int wr = w >> 1, wc = w & 1;
    f32x4 acc[4][4] = {};
    const int lrow = l >> 2;
    const int lcol = (l & 3) * 8;
    for (int k0 = 0; k0 < K; k0 += 32) {
#pragma unroll
        for (int r = 0; r < 2; ++r) {
            int ci = w * 2 + r;
            const unsigned short* ga = A + (size_t)(bm + ci * 16 + lrow) * K + k0 + lcol;
            __builtin_amdgcn_global_load_lds(
                (const __attribute__((address_space(1))) void*)ga,
                (__attribute__((address_space(3))) void*)(As + ci * 512), 16, 0, 0);
            const unsigned short* gb = Bw + (size_t)(bn + ci * 16 + lrow) * K + k0 + lcol;
            __builtin_amdgcn_global_load_lds(
                (const __attribute__((address_space(1))) void*)gb,
                (__attribute__((address_space(3))) void*)(Bs + ci * 512), 16, 0, 0);
        }
        __syncthreads();
        bf16x8 av[4], bv[4];
#pragma unroll
        for (int i = 0; i < 4; ++i)
            av[i] = *(const bf16x8*)(As + (wr * 64 + i * 16 + c) * 32 + g * 8);
#pragma unroll
        for (int j = 0; j < 4; ++j)
            bv[j] = *(const bf16x8*)(Bs + (wc * 64 + j * 16 + c) * 32 + g * 8);
#pragma unroll
        for (int i = 0; i < 4; ++i)
#pragma unroll
            for (int j = 0; j < 4; ++j)
                acc[i][j] = __builtin_amdgcn_mfma_f32_16x16x32_bf16(av[i], bv[j], acc[i][j], 0, 0, 0);
        __syncthreads();
    }
#pragma unroll
    for (int i = 0; i < 4; ++i)
#pragma unroll
        for (int j = 0; j < 4; ++j)
#pragma unroll
            for (int r = 0; r < 4; ++r) {
                int row = bm + wr * 64 + i * 16 + g * 4 + r;
                int col = bn + wc * 64 + j * 16 + c;
                float v = acc[i][j][r];
                if constexpr (sizeof(OutT) == 2)
                    Y[(size_t)row * ldy + col] = (OutT)f2bf(v);
                else
                    Y[(size_t)row * ldy + col] = v;
            }
}

// ---------------- RoPE + RMSNorm in place on bf16 qkv (stride 768, q+k only) ----------------
__global__ __launch_bounds__(256) void rope_norm_kernel(
    unsigned short* __restrict__ qkv, const float* __restrict__ cosT,
    const float* __restrict__ sinT, const float* __restrict__ gainp) {
    const int nheads = H_ + KV_;
    int gid = (blockIdx.x * blockDim.x + threadIdx.x) >> 5;
    int lane = threadIdx.x & 31;
    if (gid >= B_ * S_ * nheads) return;
    int hh = gid % nheads;
    int bs = gid / nheads;
    int s = bs % S_;
    unsigned short* row = qkv + (size_t)bs * 768;
    int off = (hh < H_) ? hh * 64 : 512 + (hh - H_) * 64;
    union { unsigned u; float f; } u1, u2;
    u1.u = ((unsigned)row[off + lane]) << 16;
    u2.u = ((unsigned)row[off + 32 + lane]) << 16;
    float c = cosT[s * 32 + lane];
    float sn = sinT[s * 32 + lane];
    float y1 = u1.f * c + u2.f * sn;
    float y2 = u2.f * c - u1.f * sn;
    float ss = y1 * y1 + y2 * y2;
#pragma unroll
    for (int m = 16; m >= 1; m >>= 1) ss += __shfl_xor(ss, m, 64);
    float scale = rsqrtf(ss * (1.0f / 64.0f) + 1e-6f);
    if (hh < H_) scale *= *gainp;
    row[off + lane] = f2bf(y1 * scale);
    row[off + 32 + lane] = f2bf(y2 * scale);
}

// ---------------- MFMA flash attention v2 ----------------
// fixed-shift softmax (scores bounded: |s|*0.125 <= 12), dbuf global_load_lds staging,
// pre-swizzled global source so LDS stays linear (m173), 1 barrier/iter.
#define SWZF(row) ((((row) + ((row) >> 3)) & 7) << 4)

__global__ __launch_bounds__(256) void attn_mfma(const unsigned short* __restrict__ qkv,
                                                 const unsigned short* __restrict__ vt,
                                                 unsigned short* __restrict__ aout) {
    __shared__ unsigned short Qs[64 * 64];
    __shared__ unsigned short Ks[2][64 * 64];
    __shared__ unsigned short Vts[2][64 * 64];   // [d][key]
    __shared__ unsigned short Ps[64 * 64];

    const int bid = blockIdx.x;
    const int bh = bid & 15;
    const int qt = 31 - (bid >> 4);   // long blocks first
    const int h = bh & 7;
    const int b = bh >> 3;
    const int kvh = h >> 1;

    const int t = threadIdx.x;
    const int w = t >> 6;
    const int l = t & 63;
    const int g = l >> 4;
    const int c = l & 15;

    // per-lane staging coords for the two 256-chunk phases
    const int row0 = (w * 64 + l) >> 3;          // phase 0 row
    const int row1 = (256 + w * 64 + l) >> 3;    // phase 1 row
    const int seg = l & 7;
    const int off0 = (seg * 16) ^ SWZF(row0);
    const int off1 = (seg * 16) ^ SWZF(row1);
    const int cb0 = (w * 64) * 16;               // LDS byte base, phase 0
    const int cb1 = (256 + w * 64) * 16;

    // ---- stage Q (once) ----
    {
        const char* qb = (const char*)(qkv + ((size_t)(b * S_ + qt * 64)) * 768 + h * 64);
        __builtin_amdgcn_global_load_lds(
            (const __attribute__((address_space(1))) void*)(qb + (size_t)row0 * 1536 + off0),
            (__attribute__((address_space(3))) void*)((char*)Qs + cb0), 16, 0, 0);
        __builtin_amdgcn_global_load_lds(
            (const __attribute__((address_space(1))) void*)(qb + (size_t)row1 * 1536 + off1),
            (__attribute__((address_space(3))) void*)((char*)Qs + cb1), 16, 0, 0);
    }

    const char* kb = (const char*)qkv + ((size_t)(b * S_)) * 1536 + 1024 + kvh * 128;
    const char* vb = (const char*)vt + ((size_t)(kvh * 64)) * 8192 + (size_t)(b * S_) * 2;

#define STAGE(kt_, bufi_)                                                                        \
    do {                                                                                         \
        const char* ks_ = kb + (size_t)(kt_) * 64 * 1536;                                        \
        const char* vs_ = vb + (size_t)(kt_) * 128;                                              \
        __builtin_amdgcn_global_load_lds(                                                        \
            (const __attribute__((address_space(1))) void*)(ks_ + (size_t)row0 * 1536 + off0),   \
            (__attribute__((address_space(3))) void*)((char*)Ks[bufi_] + cb0), 16, 0, 0);        \
        __builtin_amdgcn_global_load_lds(                                                        \
            (const __attribute__((address_space(1))) void*)(ks_ + (size_t)row1 * 1536 + off1),   \
            (__attribute__((address_space(3))) void*)((char*)Ks[bufi_] + cb1), 16, 0, 0);        \
        __builtin_amdgcn_global_load_lds(                                                        \
            (const __attribute__((address_space(1))) void*)(vs_ + (size_t)row0 * 8192 + off0),   \
            (__attribute__((address_space(3))) void*)((char*)Vts[bufi_] + cb0), 16, 0, 0);       \
        __builtin_amdgcn_global_load_lds(                                                        \
            (const __attribute__((address_space(1))) void*)(vs_ + (size_t)row1 * 8192 + off1),   \
            (__attribute__((address_space(3))) void*)((char*)Vts[bufi_] + cb1), 16, 0, 0);       \
    } while (0)

    STAGE(0, 0);
    __syncthreads();   // drains vmcnt(0): Q + tile 0 ready

    // ---- Q fragments ----
    bf16x8 aq0, aq1;
    {
        int row = w * 16 + c;
        int fx = SWZF(row);
        aq0 = *(const bf16x8*)((const char*)Qs + row * 128 + ((g * 16) ^ fx));
        aq1 = *(const bf16x8*)((const char*)Qs + row * 128 + ((64 + g * 16) ^ fx));
    }

    float l_part[4] = {0.f, 0.f, 0.f, 0.f};
    f32x4 o_acc[4] = {};
    const float LS = 0.125f * 1.4426950408889634f;   // scale * log2(e)
    const float SH = 6.0f * 1.4426950408889634f;     // fixed shift (log2 units)

    int buf = 0;
    for (int kt = 0; kt <= qt; ++kt) {
        if (kt < qt) STAGE(kt + 1, buf ^ 1);

        // ---- S = Q K^T ----
        f32x4 sA[4];
#pragma unroll
        for (int nt = 0; nt < 4; ++nt) {
            int krow = nt * 16 + c;
            int fk = SWZF(krow);
            bf16x8 b0 = *(const bf16x8*)((const char*)Ks[buf] + krow * 128 + ((g * 16) ^ fk));
            bf16x8 b1 = *(const bf16x8*)((const char*)Ks[buf] + krow * 128 + ((64 + g * 16) ^ fk));
            f32x4 acc = {0.f, 0.f, 0.f, 0.f};
            acc = __builtin_amdgcn_mfma_f32_16x16x32_bf16(aq0, b0, acc, 0, 0, 0);
            acc = __builtin_amdgcn_mfma_f32_16x16x32_bf16(aq1, b1, acc, 0, 0, 0);
            sA[nt] = acc;
        }

        // ---- fixed-shift softmax: p = exp(s*0.125 - 6), no max-tracking, no rescale ----
#pragma unroll
        for (int nt = 0; nt < 4; ++nt) {
            int key = kt * 64 + nt * 16 + c;
#pragma unroll
            for (int r = 0; r < 4; ++r) {
                int qrow = qt * 64 + w * 16 + g * 4 + r;
                float e = exp2f(sA[nt][r] * LS - SH);
                float p = (key <= qrow) ? e : 0.0f;
                unsigned pu = __float_as_uint(p) & 0xFFFF0000u;
                l_part[r] += __uint_as_float(pu);        // denominator = truncated p
                int prow = w * 16 + g * 4 + r;
                *(unsigned short*)((char*)Ps + prow * 128 + (((nt * 16 + c) * 2) ^ SWZF(prow))) =
                    (unsigned short)(pu >> 16);
            }
        }

        // ---- O += P V ----
        {
            int prow = w * 16 + c;
            int fp = SWZF(prow);
            bf16x8 pa0 = *(const bf16x8*)((const char*)Ps + prow * 128 + ((g * 16) ^ fp));
            bf16x8 pa1 = *(const bf16x8*)((const char*)Ps + prow * 128 + ((64 + g * 16) ^ fp));
#pragma unroll
            for (int nt = 0; nt < 4; ++nt) {
                int drow = nt * 16 + c;
                int fv = SWZF(drow);
                bf16x8 vb0 = *(const bf16x8*)((const char*)Vts[buf] + drow * 128 + ((g * 16) ^ fv));
                bf16x8 vb1 = *(const bf16x8*)((const char*)Vts[buf] + drow * 128 + ((64 + g * 16) ^ fv));
                o_acc[nt] = __builtin_amdgcn_mfma_f32_16x16x32_bf16(pa0, vb0, o_acc[nt], 0, 0, 0);
                o_acc[nt] = __builtin_amdgcn_mfma_f32_16x16x32_bf16(pa1, vb1, o_acc[nt], 0, 0, 0);
            }
        }
        __syncthreads();   // next tile staged + all waves done with buf
        buf ^= 1;
    }
#undef STAGE

    // ---- epilogue: deferred l reduce, O /= l, write bf16 ----
    unsigned short* ob = aout + ((size_t)(b * S_ + qt * 64 + w * 16)) * (H_ * HD_) + h * 64;
#pragma unroll
    for (int r = 0; r < 4; ++r) {
        float ls = l_part[r];
        ls += __shfl_xor(ls, 1, 64);
        ls += __shfl_xor(ls, 2, 64);
        ls += __shfl_xor(ls, 4, 64);
        ls += __shfl_xor(ls, 8, 64);
        float inv = 1.0f / ls;
#pragma unroll
        for (int nt = 0; nt < 4; ++nt)
            ob[(size_t)(g * 4 + r) * (H_ * HD_) + nt * 16 + c] = f2bf(o_acc[nt][r] * inv);
    }
}

extern "C" void kernel_launch(void* const* d_in, const int* in_sizes, int n_in,
                              void* d_out, int out_size, void* d_ws, size_t ws_size,
                              hipStream_t stream) {
    const float* x    = (const float*)d_in[0];
    const float* wq   = (const float*)d_in[1];
    const float* wk   = (const float*)d_in[2];
    const float* wv   = (const float*)d_in[3];
    const float* wo   = (const float*)d_in[4];
    const float* gain = (const float*)d_in[5];
    float* out = (float*)d_out;

    char* ws = (char*)d_ws;
    unsigned short* qkv    = (unsigned short*)(ws);                              // 6 MB: 4096x768
    unsigned short* vt     = (unsigned short*)(ws + (size_t)6  * 1024 * 1024);   // 2 MB: 256x4096
    unsigned short* aout   = (unsigned short*)(ws + (size_t)8  * 1024 * 1024);   // 4 MB: 4096x512
    unsigned short* xb     = (unsigned short*)(ws + (size_t)12 * 1024 * 1024);   // 4 MB: 4096x512
    unsigned short* wqkv_b = (unsigned short*)(ws + (size_t)16 * 1024 * 1024);   // 1 MB: 1024x512
    unsigned short* wo_b   = (unsigned short*)(ws + (size_t)17 * 1024 * 1024);   // 0.5 MB
    float* cosT            = (float*)(ws + (size_t)18 * 1024 * 1024);
    float* sinT            = cosT + (size_t)S_ * (HD_ / 2);

    rope_table_kernel<<<(S_ * (HD_ / 2) + 255) / 256, 256, 0, stream>>>(cosT, sinT);
    convert_pack_kernel<<<(2883584 / 4) / 256, 256, 0, stream>>>(x, wq, wk, wv, wo,
                                                                 xb, wqkv_b, wo_b);
    // QK projection: [4096x512] @ [768x512]^T -> qkv (stride 768)
    gemm_mfma<unsigned short><<<dim3(6, 32), 256, 0, stream>>>(xb, wqkv_b, qkv, 512, 768);
    // V^T projection: [256x512](wv) @ [4096x512](x)^T -> vt[256][4096]
    gemm_mfma<unsigned short><<<dim3(32, 2), 256, 0, stream>>>(wqkv_b + 768 * 512, xb, vt, 512, 4096);
    rope_norm_kernel<<<(B_ * S_ * 12 * 32) / 256, 256, 0, stream>>>(qkv, cosT, sinT, gain);
    attn_mfma<<<16 * (S_ / 64), 256, 0, stream>>>(qkv, vt, aout);
    gemm_mfma<float><<<dim3(4, 32), 256, 0, stream>>>(aout, wo_b, out, 512, 512);
}

// Round 5
// 86.584 us; speedup vs baseline: 15.1754x; 1.1387x over previous
//
#include <hip/hip_runtime.h>
#include <math.h>

#define B_ 2
#define S_ 2048
#define D_ 512
#define H_ 8
#define KV_ 4
#define HD_ 64
// qkv row (bf16, stride 768): [q(512) | k(256)] ; V transposed in vt[256][4096]

typedef __attribute__((ext_vector_type(8))) short bf16x8;
typedef __attribute__((ext_vector_type(4))) short bf16x4;
typedef __attribute__((ext_vector_type(4))) float f32x4;
typedef __attribute__((ext_vector_type(16))) float f32x16;
typedef __attribute__((ext_vector_type(4))) unsigned u32x4;

static __device__ __forceinline__ unsigned short f2bf(float f) {
    union { float f; unsigned u; } v; v.f = f;
    unsigned r = v.u + 0x7FFFu + ((v.u >> 16) & 1);
    return (unsigned short)(r >> 16);
}

// ---------------- RoPE tables ----------------
__global__ void rope_table_kernel(float* __restrict__ cosT, float* __restrict__ sinT) {
    int idx = blockIdx.x * blockDim.x + threadIdx.x;
    if (idx >= S_ * (HD_ / 2)) return;
    int s = idx >> 5;
    int i = idx & 31;
    float invf = 1.0f / powf(10000.0f, (float)(2 * i) / (float)HD_);
    float arg = (float)s * invf;
    double a = (double)arg;
    cosT[idx] = (float)cos(a);
    sinT[idx] = (float)sin(a);
}

// ---------------- fp32 -> bf16 pack: x ; wq|wk|wv fused ; wo ----------------
__global__ __launch_bounds__(256) void convert_pack_kernel(
    const float* __restrict__ x, const float* __restrict__ wq, const float* __restrict__ wk,
    const float* __restrict__ wv, const float* __restrict__ wo,
    unsigned short* __restrict__ xb, unsigned short* __restrict__ wqkv_b,
    unsigned short* __restrict__ wo_b) {
    int i4 = blockIdx.x * blockDim.x + threadIdx.x;
    int e = i4 * 4;
    const float* src;
    unsigned short* dst;
    if (e < 2097152)      { src = x + e;               dst = xb + e; }
    else if (e < 2359296) { src = wq + (e - 2097152);  dst = wqkv_b + (e - 2097152); }
    else if (e < 2490368) { src = wk + (e - 2359296);  dst = wqkv_b + (e - 2097152); }
    else if (e < 2621440) { src = wv + (e - 2490368);  dst = wqkv_b + (e - 2097152); }
    else                  { src = wo + (e - 2621440);  dst = wo_b + (e - 2621440); }
    float4 v = *(const float4*)src;
    bf16x4 o;
    o[0] = (short)f2bf(v.x); o[1] = (short)f2bf(v.y);
    o[2] = (short)f2bf(v.z); o[3] = (short)f2bf(v.w);
    *(bf16x4*)dst = o;
}

// ---------------- bf16 MFMA GEMM: Y[m][n] = sum_k A[m][k]*Bw[n][k] ----------------
template <typename OutT>
__global__ __launch_bounds__(256) void gemm_mfma(
    const unsigned short* __restrict__ A, const unsigned short* __restrict__ Bw,
    OutT* __restrict__ Y, int K, int ldy) {
    __shared__ unsigned short As[128 * 32];
    __shared__ unsigned short Bs[128 * 32];
    const int bn = blockIdx.x * 128;
    const int bm = blockIdx.y * 128;
    const int t = threadIdx.x;
    const int w = t >> 6, l = t & 63;
    const int g = l >> 4, c = l & 15;
    const int wr = w >> 1, wc = w & 1;
    f32x4 acc[4][4] = {};
    const int lrow = l >> 2;
    const int lcol = (l & 3) * 8;
    for (int k0 = 0; k0 < K; k0 += 32) {
#pragma unroll
        for (int r = 0; r < 2; ++r) {
            int ci = w * 2 + r;
            const unsigned short* ga = A + (size_t)(bm + ci * 16 + lrow) * K + k0 + lcol;
            __builtin_amdgcn_global_load_lds(
                (const __attribute__((address_space(1))) void*)ga,
                (__attribute__((address_space(3))) void*)(As + ci * 512), 16, 0, 0);
            const unsigned short* gb = Bw + (size_t)(bn + ci * 16 + lrow) * K + k0 + lcol;
            __builtin_amdgcn_global_load_lds(
                (const __attribute__((address_space(1))) void*)gb,
                (__attribute__((address_space(3))) void*)(Bs + ci * 512), 16, 0, 0);
        }
        __syncthreads();
        bf16x8 av[4], bv[4];
#pragma unroll
        for (int i = 0; i < 4; ++i)
            av[i] = *(const bf16x8*)(As + (wr * 64 + i * 16 + c) * 32 + g * 8);
#pragma unroll
        for (int j = 0; j < 4; ++j)
            bv[j] = *(const bf16x8*)(Bs + (wc * 64 + j * 16 + c) * 32 + g * 8);
#pragma unroll
        for (int i = 0; i < 4; ++i)
#pragma unroll
            for (int j = 0; j < 4; ++j)
                acc[i][j] = __builtin_amdgcn_mfma_f32_16x16x32_bf16(av[i], bv[j], acc[i][j], 0, 0, 0);
        __syncthreads();
    }
#pragma unroll
    for (int i = 0; i < 4; ++i)
#pragma unroll
        for (int j = 0; j < 4; ++j)
#pragma unroll
            for (int r = 0; r < 4; ++r) {
                int row = bm + wr * 64 + i * 16 + g * 4 + r;
                int col = bn + wc * 64 + j * 16 + c;
                float v = acc[i][j][r];
                if constexpr (sizeof(OutT) == 2)
                    Y[(size_t)row * ldy + col] = (OutT)f2bf(v);
                else
                    Y[(size_t)row * ldy + col] = v;
            }
}

// ---------------- RoPE + RMSNorm in place on bf16 qkv (stride 768) ----------------
__global__ __launch_bounds__(256) void rope_norm_kernel(
    unsigned short* __restrict__ qkv, const float* __restrict__ cosT,
    const float* __restrict__ sinT, const float* __restrict__ gainp) {
    const int nheads = H_ + KV_;
    int gid = (blockIdx.x * blockDim.x + threadIdx.x) >> 5;
    int lane = threadIdx.x & 31;
    if (gid >= B_ * S_ * nheads) return;
    int hh = gid % nheads;
    int bs = gid / nheads;
    int s = bs % S_;
    unsigned short* row = qkv + (size_t)bs * 768;
    int off = (hh < H_) ? hh * 64 : 512 + (hh - H_) * 64;
    union { unsigned u; float f; } u1, u2;
    u1.u = ((unsigned)row[off + lane]) << 16;
    u2.u = ((unsigned)row[off + 32 + lane]) << 16;
    float c = cosT[s * 32 + lane];
    float sn = sinT[s * 32 + lane];
    float y1 = u1.f * c + u2.f * sn;
    float y2 = u2.f * c - u1.f * sn;
    float ss = y1 * y1 + y2 * y2;
#pragma unroll
    for (int m = 16; m >= 1; m >>= 1) ss += __shfl_xor(ss, m, 64);
    float scale = rsqrtf(ss * (1.0f / 64.0f) + 1e-6f);
    if (hh < H_) scale *= *gainp;
    row[off + lane] = f2bf(y1 * scale);
    row[off + 32 + lane] = f2bf(y2 * scale);
}

// ---------------- MFMA flash attention v3: 32x32 swapped-QK, zero P round-trip ----------------
// block = (b, head, 64-row q-tile); 4 waves = 2(q-half) x 2(key-half).
// S^T = mfma(K, Q): lane&31 = q-row, (reg&3)+8(reg>>2)+4(lane>>5) = key.
// P -> bf16 via v_cvt_pk_bf16_f32; PV A-frags assembled with v_permlane32_swap_b32.
#define SWZF(row) ((((row) + ((row) >> 3)) & 7) << 4)

__global__ __launch_bounds__(256, 3) void attn_mfma(const unsigned short* __restrict__ qkv,
                                                    const unsigned short* __restrict__ vt,
                                                    unsigned short* __restrict__ aout) {
    __shared__ alignas(128) char smem[40960];
    // [0,8K): Qs ; [8K,24K): Ks dbuf ; [24K,40K): Vts dbuf
    // epilogue overlay: Os f32[2*32][64] at +8K (16KB), Ls f32[128] at +24K

    const int bid = blockIdx.x;
    const int bh = bid & 15;
    const int qt = 31 - (bid >> 4);   // long blocks first
    const int hh = bh & 7;
    const int b = bh >> 3;
    const int kvh = hh >> 1;

    const int t = threadIdx.x;
    const int w = t >> 6;
    const int l = t & 63;
    const int wq = w >> 1;   // q-half: rows [32wq, 32wq+32)
    const int wk = w & 1;    // key-half: keys [32wk, 32wk+32)
    const int hl = l >> 5;
    const int l31 = l & 31;

    // staging coords (pre-swizzled global source, linear LDS dest)
    const int row0 = t >> 3;
    const int row1 = (256 + t) >> 3;
    const int seg = l & 7;
    const int off0 = (seg * 16) ^ SWZF(row0);
    const int off1 = (seg * 16) ^ SWZF(row1);
    const int cb0 = w * 1024;
    const int cb1 = 4096 + w * 1024;

    // ---- stage Q ----
    {
        const char* qb = (const char*)(qkv + ((size_t)(b * S_ + qt * 64)) * 768 + hh * 64);
        __builtin_amdgcn_global_load_lds(
            (const __attribute__((address_space(1))) void*)(qb + (size_t)row0 * 1536 + off0),
            (__attribute__((address_space(3))) void*)(smem + cb0), 16, 0, 0);
        __builtin_amdgcn_global_load_lds(
            (const __attribute__((address_space(1))) void*)(qb + (size_t)row1 * 1536 + off1),
            (__attribute__((address_space(3))) void*)(smem + cb1), 16, 0, 0);
    }

    const char* kb = (const char*)qkv + ((size_t)(b * S_)) * 1536 + 1024 + kvh * 128;
    const char* vb = (const char*)vt + ((size_t)(kvh * 64)) * 8192 + (size_t)(b * S_) * 2;

#define STAGE(kt_, bufi_)                                                                        \
    do {                                                                                         \
        const char* ks_ = kb + (size_t)(kt_) * 64 * 1536;                                        \
        const char* vs_ = vb + (size_t)(kt_) * 128;                                              \
        char* kd_ = smem + 8192 + (bufi_)*8192;                                                  \
        char* vd_ = smem + 24576 + (bufi_)*8192;                                                 \
        __builtin_amdgcn_global_load_lds(                                                        \
            (const __attribute__((address_space(1))) void*)(ks_ + (size_t)row0 * 1536 + off0),   \
            (__attribute__((address_space(3))) void*)(kd_ + cb0), 16, 0, 0);                     \
        __builtin_amdgcn_global_load_lds(                                                        \
            (const __attribute__((address_space(1))) void*)(ks_ + (size_t)row1 * 1536 + off1),   \
            (__attribute__((address_space(3))) void*)(kd_ + cb1), 16, 0, 0);                     \
        __builtin_amdgcn_global_load_lds(                                                        \
            (const __attribute__((address_space(1))) void*)(vs_ + (size_t)row0 * 8192 + off0),   \
            (__attribute__((address_space(3))) void*)(vd_ + cb0), 16, 0, 0);                     \
        __builtin_amdgcn_global_load_lds(                                                        \
            (const __attribute__((address_space(1))) void*)(vs_ + (size_t)row1 * 8192 + off1),   \
            (__attribute__((address_space(3))) void*)(vd_ + cb1), 16, 0, 0);                     \
    } while (0)

    STAGE(0, 0);
    __syncthreads();   // Q + tile 0 staged

    // ---- hoist Q B-frags: B[col=q][k=d], q = 32wq + l31 ----
    bf16x8 qf[4];
    {
        int row = wq * 32 + l31;
        int fx = SWZF(row);
#pragma unroll
        for (int kd = 0; kd < 4; ++kd)
            qf[kd] = *(const bf16x8*)(smem + row * 128 + ((kd * 32 + hl * 16) ^ fx));
    }

    float l_part = 0.0f;
    f32x16 o_acc[2] = {};
    const float LS = 0.125f * 1.4426950408889634f;
    const float SH = 6.0f * 1.4426950408889634f;

    int buf = 0;
    for (int kt = 0; kt <= qt; ++kt) {
        if (kt < qt) STAGE(kt + 1, buf ^ 1);
        const char* KsB = smem + 8192 + buf * 8192;
        const char* VtB = smem + 24576 + buf * 8192;
        const bool diag = (kt == qt);

        if (!(diag && wk > wq)) {
            // ---- S^T = mfma(K, Q): A[row=key][k=d] ----
            f32x16 s_acc = {};
            {
                int arow = wk * 32 + l31;
                int af = SWZF(arow);
                __builtin_amdgcn_s_setprio(1);
#pragma unroll
                for (int kd = 0; kd < 4; ++kd) {
                    bf16x8 afr = *(const bf16x8*)(KsB + arow * 128 + ((kd * 32 + hl * 16) ^ af));
                    s_acc = __builtin_amdgcn_mfma_f32_32x32x16_bf16(afr, qf[kd], s_acc, 0, 0, 0);
                }
                __builtin_amdgcn_s_setprio(0);
            }
            // ---- prefetch V B-frags (independent of softmax) ----
            bf16x8 vf[2][2];
#pragma unroll
            for (int nd = 0; nd < 2; ++nd) {
                int vr = nd * 32 + l31;
                int fv = SWZF(vr);
#pragma unroll
                for (int m = 0; m < 2; ++m)
                    vf[nd][m] = *(const bf16x8*)(VtB + vr * 128 + ((wk * 64 + m * 32 + hl * 16) ^ fv));
            }
            // ---- fixed-shift softmax: p = exp2(s*LS - SH), lane-local ----
            float p[16];
            if (diag && wk == wq) {
#pragma unroll
                for (int idx = 0; idx < 16; ++idx) {
                    int keyin = 4 * hl + 8 * (idx >> 2) + (idx & 3);
                    float e = exp2f(s_acc[idx] * LS - SH);
                    p[idx] = (keyin <= l31) ? e : 0.0f;
                }
            } else {
#pragma unroll
                for (int idx = 0; idx < 16; ++idx)
                    p[idx] = exp2f(s_acc[idx] * LS - SH);
            }
#pragma unroll
            for (int idx = 0; idx < 16; ++idx) l_part += p[idx];
            // ---- pack to bf16 pairs: pw[s*2+j] = keys (8s+4hl+2j, +1) ----
            unsigned pw[8];
#pragma unroll
            for (int s = 0; s < 4; ++s)
#pragma unroll
                for (int j = 0; j < 2; ++j)
                    asm("v_cvt_pk_bf16_f32 %0, %1, %2"
                        : "=v"(pw[s * 2 + j])
                        : "v"(p[4 * s + 2 * j]), "v"(p[4 * s + 2 * j + 1]));
            // ---- permlane32_swap assembles PV A-frags in-place ----
            // after swap(pw[4m]<->pw[4m+2], pw[4m+1]<->pw[4m+3]), frag_m = pw[4m..4m+3]
#pragma unroll
            for (int m = 0; m < 2; ++m) {
                asm volatile("v_permlane32_swap_b32 %0, %1" : "+v"(pw[4 * m + 0]), "+v"(pw[4 * m + 2]));
                asm volatile("v_permlane32_swap_b32 %0, %1" : "+v"(pw[4 * m + 1]), "+v"(pw[4 * m + 3]));
            }
            // ---- O += P V : A[q][k=key], B[col=d][k=key] ----
            __builtin_amdgcn_s_setprio(1);
#pragma unroll
            for (int m = 0; m < 2; ++m) {
                u32x4 fu = {pw[4 * m + 0], pw[4 * m + 1], pw[4 * m + 2], pw[4 * m + 3]};
                bf16x8 pfr = *(bf16x8*)&fu;
#pragma unroll
                for (int nd = 0; nd < 2; ++nd)
                    o_acc[nd] = __builtin_amdgcn_mfma_f32_32x32x16_bf16(pfr, vf[nd][m], o_acc[nd], 0, 0, 0);
            }
            __builtin_amdgcn_s_setprio(0);
        }
        __syncthreads();
        buf ^= 1;
    }
#undef STAGE

    // ---- epilogue: cross-wk O/l reduce via LDS overlay, normalize, store ----
    float* Os = (float*)(smem + 8192);
    float* Ls = (float*)(smem + 24576);
    float lsum = l_part + __shfl_xor(l_part, 32, 64);
    if (hl == 0) Ls[wk * 64 + wq * 32 + l31] = lsum;
    if (wk == 0) {
#pragma unroll
        for (int nd = 0; nd < 2; ++nd)
#pragma unroll
            for (int reg = 0; reg < 16; ++reg) {
                int qrow = 4 * hl + 8 * (reg >> 2) + (reg & 3);
                Os[(wq * 32 + qrow) * 64 + nd * 32 + l31] = o_acc[nd][reg];
            }
    }
    __syncthreads();
    if (wk == 1) {
        unsigned short* ob = aout + ((size_t)(b * S_ + qt * 64 + wq * 32)) * 512 + hh * 64;
#pragma unroll
        for (int reg = 0; reg < 16; ++reg) {
            int qrow = 4 * hl + 8 * (reg >> 2) + (reg & 3);
            float ltot = Ls[wq * 32 + qrow] + Ls[64 + wq * 32 + qrow];
            float inv = __builtin_amdgcn_rcpf(ltot);
#pragma unroll
            for (int nd = 0; nd < 2; ++nd) {
                float val = (o_acc[nd][reg] + Os[(wq * 32 + qrow) * 64 + nd * 32 + l31]) * inv;
                ob[(size_t)qrow * 512 + nd * 32 + l31] = f2bf(val);
            }
        }
    }
}

extern "C" void kernel_launch(void* const* d_in, const int* in_sizes, int n_in,
                              void* d_out, int out_size, void* d_ws, size_t ws_size,
                              hipStream_t stream) {
    const float* x    = (const float*)d_in[0];
    const float* wq   = (const float*)d_in[1];
    const float* wk   = (const float*)d_in[2];
    const float* wv   = (const float*)d_in[3];
    const float* wo   = (const float*)d_in[4];
    const float* gain = (const float*)d_in[5];
    float* out = (float*)d_out;

    char* ws = (char*)d_ws;
    unsigned short* qkv    = (unsigned short*)(ws);                              // 6 MB: 4096x768
    unsigned short* vt     = (unsigned short*)(ws + (size_t)6  * 1024 * 1024);   // 2 MB: 256x4096
    unsigned short* aout   = (unsigned short*)(ws + (size_t)8  * 1024 * 1024);   // 4 MB: 4096x512
    unsigned short* xb     = (unsigned short*)(ws + (size_t)12 * 1024 * 1024);   // 4 MB: 4096x512
    unsigned short* wqkv_b = (unsigned short*)(ws + (size_t)16 * 1024 * 1024);   // 1 MB: 1024x512
    unsigned short* wo_b   = (unsigned short*)(ws + (size_t)17 * 1024 * 1024);   // 0.5 MB
    float* cosT            = (float*)(ws + (size_t)18 * 1024 * 1024);
    float* sinT            = cosT + (size_t)S_ * (HD_ / 2);

    rope_table_kernel<<<(S_ * (HD_ / 2) + 255) / 256, 256, 0, stream>>>(cosT, sinT);
    convert_pack_kernel<<<(2883584 / 4) / 256, 256, 0, stream>>>(x, wq, wk, wv, wo,
                                                                 xb, wqkv_b, wo_b);
    // QK projection: [4096x512] @ [768x512]^T -> qkv (stride 768)
    gemm_mfma<unsigned short><<<dim3(6, 32), 256, 0, stream>>>(xb, wqkv_b, qkv, 512, 768);
    // V^T projection: [256x512](wv) @ [4096x512](x)^T -> vt[256][4096]
    gemm_mfma<unsigned short><<<dim3(32, 2), 256, 0, stream>>>(wqkv_b + 768 * 512, xb, vt, 512, 4096);
    rope_norm_kernel<<<(B_ * S_ * 12 * 32) / 256, 256, 0, stream>>>(qkv, cosT, sinT, gain);
    attn_mfma<<<16 * (S_ / 64), 256, 0, stream>>>(qkv, vt, aout);
    gemm_mfma<float><<<dim3(4, 32), 256, 0, stream>>>(aout, wo_b, out, 512, 512);
}

// Round 6
// 79.159 us; speedup vs baseline: 16.5988x; 1.0938x over previous
//
#include <hip/hip_runtime.h>
#include <math.h>

#define B_ 2
#define S_ 2048
#define D_ 512
#define H_ 8
#define KV_ 4
#define HD_ 64
// qkv row (bf16, stride 768): [q(512) | k(256)] ; V transposed in vt[256][4096]

typedef __attribute__((ext_vector_type(8))) short bf16x8;
typedef __attribute__((ext_vector_type(4))) short bf16x4;
typedef __attribute__((ext_vector_type(4))) float f32x4;
typedef __attribute__((ext_vector_type(16))) float f32x16;
typedef __attribute__((ext_vector_type(4))) unsigned u32x4;

static __device__ __forceinline__ unsigned short f2bf(float f) {
    union { float f; unsigned u; } v; v.f = f;
    unsigned r = v.u + 0x7FFFu + ((v.u >> 16) & 1);
    return (unsigned short)(r >> 16);
}

// ---------------- fp32 -> bf16 pack (x ; wq|wk|wv fused ; wo) + RoPE tables ----------------
// blocks [0,2816): convert 4 elems/thread ; blocks [2816,3072): rope table 1 entry/thread
__global__ __launch_bounds__(256) void convert_pack_kernel(
    const float* __restrict__ x, const float* __restrict__ wq, const float* __restrict__ wk,
    const float* __restrict__ wv, const float* __restrict__ wo,
    unsigned short* __restrict__ xb, unsigned short* __restrict__ wqkv_b,
    unsigned short* __restrict__ wo_b, float* __restrict__ cosT, float* __restrict__ sinT) {
    if (blockIdx.x >= 2816) {
        int idx = (blockIdx.x - 2816) * 256 + threadIdx.x;   // [0, 65536)
        int s = idx >> 5;
        int i = idx & 31;
        float invf = 1.0f / powf(10000.0f, (float)(2 * i) / (float)HD_);
        double a = (double)((float)s * invf);
        cosT[idx] = (float)cos(a);
        sinT[idx] = (float)sin(a);
        return;
    }
    int i4 = blockIdx.x * blockDim.x + threadIdx.x;
    int e = i4 * 4;
    const float* src;
    unsigned short* dst;
    if (e < 2097152)      { src = x + e;               dst = xb + e; }
    else if (e < 2359296) { src = wq + (e - 2097152);  dst = wqkv_b + (e - 2097152); }
    else if (e < 2490368) { src = wk + (e - 2359296);  dst = wqkv_b + (e - 2097152); }
    else if (e < 2621440) { src = wv + (e - 2490368);  dst = wqkv_b + (e - 2097152); }
    else                  { src = wo + (e - 2621440);  dst = wo_b + (e - 2621440); }
    float4 v = *(const float4*)src;
    bf16x4 o;
    o[0] = (short)f2bf(v.x); o[1] = (short)f2bf(v.y);
    o[2] = (short)f2bf(v.z); o[3] = (short)f2bf(v.w);
    *(bf16x4*)dst = o;
}

// ---------------- bf16 MFMA GEMM: Y[m][n] = sum_k A[m][k]*Bw[n][k] ----------------
// EPI: 0 = fp32 store, 1 = bf16 store, 2 = bf16 store with fused RoPE + RMSNorm (+gain on q)
template <int EPI, typename OutT>
__global__ __launch_bounds__(256) void gemm_mfma(
    const unsigned short* __restrict__ A, const unsigned short* __restrict__ Bw,
    OutT* __restrict__ Y, int K, int ldy,
    const float* __restrict__ cosT, const float* __restrict__ sinT,
    const float* __restrict__ gainp) {
    __shared__ unsigned short As[128 * 32];
    __shared__ unsigned short Bs[128 * 32];
    const int bn = blockIdx.x * 128;
    const int bm = blockIdx.y * 128;
    const int t = threadIdx.x;
    const int w = t >> 6, l = t & 63;
    const int g = l >> 4, c = l & 15;
    const int wr = w >> 1, wc = w & 1;
    f32x4 acc[4][4] = {};
    const int lrow = l >> 2;
    const int lcol = (l & 3) * 8;
    for (int k0 = 0; k0 < K; k0 += 32) {
#pragma unroll
        for (int r = 0; r < 2; ++r) {
            int ci = w * 2 + r;
            const unsigned short* ga = A + (size_t)(bm + ci * 16 + lrow) * K + k0 + lcol;
            __builtin_amdgcn_global_load_lds(
                (const __attribute__((address_space(1))) void*)ga,
                (__attribute__((address_space(3))) void*)(As + ci * 512), 16, 0, 0);
            const unsigned short* gb = Bw + (size_t)(bn + ci * 16 + lrow) * K + k0 + lcol;
            __builtin_amdgcn_global_load_lds(
                (const __attribute__((address_space(1))) void*)gb,
                (__attribute__((address_space(3))) void*)(Bs + ci * 512), 16, 0, 0);
        }
        __syncthreads();
        bf16x8 av[4], bv[4];
#pragma unroll
        for (int i = 0; i < 4; ++i)
            av[i] = *(const bf16x8*)(As + (wr * 64 + i * 16 + c) * 32 + g * 8);
#pragma unroll
        for (int j = 0; j < 4; ++j)
            bv[j] = *(const bf16x8*)(Bs + (wc * 64 + j * 16 + c) * 32 + g * 8);
#pragma unroll
        for (int i = 0; i < 4; ++i)
#pragma unroll
            for (int j = 0; j < 4; ++j)
                acc[i][j] = __builtin_amdgcn_mfma_f32_16x16x32_bf16(av[i], bv[j], acc[i][j], 0, 0, 0);
        __syncthreads();
    }
    if constexpr (EPI == 2) {
        // fused RoPE + RMSNorm: wave-half = one 64-col head; pairs (d, d+32) = cols (j, j+2)
        const float gv = *gainp;
        const float hscale = ((bn + wc * 64) < 512) ? gv : 1.0f;   // q heads get gain
#pragma unroll
        for (int i = 0; i < 4; ++i) {
#pragma unroll
            for (int r = 0; r < 4; ++r) {
                int row = bm + wr * 64 + i * 16 + g * 4 + r;   // token 0..4095
                int s = row & (S_ - 1);
                float c0 = cosT[s * 32 + c],      s0 = sinT[s * 32 + c];
                float c1 = cosT[s * 32 + c + 16], s1 = sinT[s * 32 + c + 16];
                float x1a = acc[i][0][r], x1b = acc[i][1][r];
                float x2a = acc[i][2][r], x2b = acc[i][3][r];
                float y1a = x1a * c0 + x2a * s0, y2a = x2a * c0 - x1a * s0;
                float y1b = x1b * c1 + x2b * s1, y2b = x2b * c1 - x1b * s1;
                float ss = y1a * y1a + y2a * y2a + y1b * y1b + y2b * y2b;
                ss += __shfl_xor(ss, 1, 64);
                ss += __shfl_xor(ss, 2, 64);
                ss += __shfl_xor(ss, 4, 64);
                ss += __shfl_xor(ss, 8, 64);
                float sc = rsqrtf(ss * (1.0f / 64.0f) + 1e-6f) * hscale;
                unsigned short* yr = (unsigned short*)Y + (size_t)row * ldy + bn + wc * 64 + c;
                yr[0]  = f2bf(y1a * sc);
                yr[16] = f2bf(y1b * sc);
                yr[32] = f2bf(y2a * sc);
                yr[48] = f2bf(y2b * sc);
            }
        }
    } else {
#pragma unroll
        for (int i = 0; i < 4; ++i)
#pragma unroll
            for (int j = 0; j < 4; ++j)
#pragma unroll
                for (int r = 0; r < 4; ++r) {
                    int row = bm + wr * 64 + i * 16 + g * 4 + r;
                    int col = bn + wc * 64 + j * 16 + c;
                    float v = acc[i][j][r];
                    if constexpr (EPI == 1)
                        Y[(size_t)row * ldy + col] = (OutT)f2bf(v);
                    else
                        Y[(size_t)row * ldy + col] = v;
                }
    }
}

// ---------------- MFMA flash attention v3.1: 32x32 swapped-QK, Q from global ----------------
// block = (b, head, 64-row q-tile); 4 waves = 2(q-half) x 2(key-half).
// S^T = mfma(K, Q): lane&31 = q-row, (reg&3)+8(reg>>2)+4(lane>>5) = key.
#define SWZF(row) ((((row) + ((row) >> 3)) & 7) << 4)

__global__ __launch_bounds__(256, 3) void attn_mfma(const unsigned short* __restrict__ qkv,
                                                    const unsigned short* __restrict__ vt,
                                                    unsigned short* __restrict__ aout) {
    __shared__ alignas(128) char smem[32768];
    // [0,16K): Ks dbuf ; [16K,32K): Vts dbuf
    // epilogue overlay: Os f32[64][64] at 0 (16KB), Ls f32[128] at +16K

    const int bid = blockIdx.x;
    const int bh = bid & 15;
    const int qt = 31 - (bid >> 4);   // long blocks first
    const int hh = bh & 7;
    const int b = bh >> 3;
    const int kvh = hh >> 1;

    const int t = threadIdx.x;
    const int w = t >> 6;
    const int l = t & 63;
    const int wq = w >> 1;   // q-half: rows [32wq, 32wq+32)
    const int wk = w & 1;    // key-half: keys [32wk, 32wk+32)
    const int hl = l >> 5;
    const int l31 = l & 31;

    // staging coords (pre-swizzled global source, linear LDS dest)
    const int row0 = t >> 3;
    const int row1 = (256 + t) >> 3;
    const int seg = l & 7;
    const int off0 = (seg * 16) ^ SWZF(row0);
    const int off1 = (seg * 16) ^ SWZF(row1);
    const int cb0 = w * 1024;
    const int cb1 = 4096 + w * 1024;

    // ---- Q B-frags straight from global (L2-resident): B[col=q][k=d] ----
    bf16x8 qf[4];
    {
        const unsigned short* qrow =
            qkv + (size_t)(b * S_ + qt * 64 + wq * 32 + l31) * 768 + hh * 64 + hl * 8;
#pragma unroll
        for (int kd = 0; kd < 4; ++kd)
            qf[kd] = *(const bf16x8*)(qrow + kd * 16);
    }

    const char* kb = (const char*)qkv + ((size_t)(b * S_)) * 1536 + 1024 + kvh * 128;
    const char* vb = (const char*)vt + ((size_t)(kvh * 64)) * 8192 + (size_t)(b * S_) * 2;

#define STAGE(kt_, bufi_)                                                                        \
    do {                                                                                         \
        const char* ks_ = kb + (size_t)(kt_) * 64 * 1536;                                        \
        const char* vs_ = vb + (size_t)(kt_) * 128;                                              \
        char* kd_ = smem + (bufi_)*8192;                                                         \
        char* vd_ = smem + 16384 + (bufi_)*8192;                                                 \
        __builtin_amdgcn_global_load_lds(                                                        \
            (const __attribute__((address_space(1))) void*)(ks_ + (size_t)row0 * 1536 + off0),   \
            (__attribute__((address_space(3))) void*)(kd_ + cb0), 16, 0, 0);                     \
        __builtin_amdgcn_global_load_lds(                                                        \
            (const __attribute__((address_space(1))) void*)(ks_ + (size_t)row1 * 1536 + off1),   \
            (__attribute__((address_space(3))) void*)(kd_ + cb1), 16, 0, 0);                     \
        __builtin_amdgcn_global_load_lds(                                                        \
            (const __attribute__((address_space(1))) void*)(vs_ + (size_t)row0 * 8192 + off0),   \
            (__attribute__((address_space(3))) void*)(vd_ + cb0), 16, 0, 0);                     \
        __builtin_amdgcn_global_load_lds(                                                        \
            (const __attribute__((address_space(1))) void*)(vs_ + (size_t)row1 * 8192 + off1),   \
            (__attribute__((address_space(3))) void*)(vd_ + cb1), 16, 0, 0);                     \
    } while (0)

    STAGE(0, 0);
    __syncthreads();   // tile 0 staged

    float l_part = 0.0f;
    f32x16 o_acc[2] = {};
    const float LS = 0.125f * 1.4426950408889634f;
    const float SH = 6.0f * 1.4426950408889634f;

    int buf = 0;
    for (int kt = 0; kt <= qt; ++kt) {
        if (kt < qt) STAGE(kt + 1, buf ^ 1);
        const char* KsB = smem + buf * 8192;
        const char* VtB = smem + 16384 + buf * 8192;
        const bool diag = (kt == qt);

        if (!(diag && wk > wq)) {
            // ---- S^T = mfma(K, Q): A[row=key][k=d] ----
            f32x16 s_acc = {};
            {
                int arow = wk * 32 + l31;
                int af = SWZF(arow);
                __builtin_amdgcn_s_setprio(1);
#pragma unroll
                for (int kd = 0; kd < 4; ++kd) {
                    bf16x8 afr = *(const bf16x8*)(KsB + arow * 128 + ((kd * 32 + hl * 16) ^ af));
                    s_acc = __builtin_amdgcn_mfma_f32_32x32x16_bf16(afr, qf[kd], s_acc, 0, 0, 0);
                }
                __builtin_amdgcn_s_setprio(0);
            }
            // ---- prefetch V B-frags ----
            bf16x8 vf[2][2];
#pragma unroll
            for (int nd = 0; nd < 2; ++nd) {
                int vr = nd * 32 + l31;
                int fv = SWZF(vr);
#pragma unroll
                for (int m = 0; m < 2; ++m)
                    vf[nd][m] = *(const bf16x8*)(VtB + vr * 128 + ((wk * 64 + m * 32 + hl * 16) ^ fv));
            }
            // ---- fixed-shift softmax: p = exp2(s*LS - SH), lane-local ----
            float p[16];
            if (diag && wk == wq) {
#pragma unroll
                for (int idx = 0; idx < 16; ++idx) {
                    int keyin = 4 * hl + 8 * (idx >> 2) + (idx & 3);
                    float e = exp2f(s_acc[idx] * LS - SH);
                    p[idx] = (keyin <= l31) ? e : 0.0f;
                }
            } else {
#pragma unroll
                for (int idx = 0; idx < 16; ++idx)
                    p[idx] = exp2f(s_acc[idx] * LS - SH);
            }
#pragma unroll
            for (int idx = 0; idx < 16; ++idx) l_part += p[idx];
            // ---- pack to bf16 pairs ----
            unsigned pw[8];
#pragma unroll
            for (int s = 0; s < 4; ++s)
#pragma unroll
                for (int j = 0; j < 2; ++j)
                    asm("v_cvt_pk_bf16_f32 %0, %1, %2"
                        : "=v"(pw[s * 2 + j])
                        : "v"(p[4 * s + 2 * j]), "v"(p[4 * s + 2 * j + 1]));
            // ---- permlane32_swap assembles PV A-frags in-place ----
#pragma unroll
            for (int m = 0; m < 2; ++m) {
                asm volatile("v_permlane32_swap_b32 %0, %1" : "+v"(pw[4 * m + 0]), "+v"(pw[4 * m + 2]));
                asm volatile("v_permlane32_swap_b32 %0, %1" : "+v"(pw[4 * m + 1]), "+v"(pw[4 * m + 3]));
            }
            // ---- O += P V ----
            __builtin_amdgcn_s_setprio(1);
#pragma unroll
            for (int m = 0; m < 2; ++m) {
                u32x4 fu = {pw[4 * m + 0], pw[4 * m + 1], pw[4 * m + 2], pw[4 * m + 3]};
                bf16x8 pfr = *(bf16x8*)&fu;
#pragma unroll
                for (int nd = 0; nd < 2; ++nd)
                    o_acc[nd] = __builtin_amdgcn_mfma_f32_32x32x16_bf16(pfr, vf[nd][m], o_acc[nd], 0, 0, 0);
            }
            __builtin_amdgcn_s_setprio(0);
        }
        __syncthreads();
        buf ^= 1;
    }
#undef STAGE

    // ---- epilogue: cross-wk O/l reduce via LDS overlay, normalize, store ----
    float* Os = (float*)smem;
    float* Ls = (float*)(smem + 16384);
    float lsum = l_part + __shfl_xor(l_part, 32, 64);
    if (hl == 0) Ls[wk * 64 + wq * 32 + l31] = lsum;
    if (wk == 0) {
#pragma unroll
        for (int nd = 0; nd < 2; ++nd)
#pragma unroll
            for (int reg = 0; reg < 16; ++reg) {
                int qrow = 4 * hl + 8 * (reg >> 2) + (reg & 3);
                Os[(wq * 32 + qrow) * 64 + nd * 32 + l31] = o_acc[nd][reg];
            }
    }
    __syncthreads();
    if (wk == 1) {
        unsigned short* ob = aout + ((size_t)(b * S_ + qt * 64 + wq * 32)) * 512 + hh * 64;
#pragma unroll
        for (int reg = 0; reg < 16; ++reg) {
            int qrow = 4 * hl + 8 * (reg >> 2) + (reg & 3);
            float ltot = Ls[wq * 32 + qrow] + Ls[64 + wq * 32 + qrow];
            float inv = __builtin_amdgcn_rcpf(ltot);
#pragma unroll
            for (int nd = 0; nd < 2; ++nd) {
                float val = (o_acc[nd][reg] + Os[(wq * 32 + qrow) * 64 + nd * 32 + l31]) * inv;
                ob[(size_t)qrow * 512 + nd * 32 + l31] = f2bf(val);
            }
        }
    }
}

extern "C" void kernel_launch(void* const* d_in, const int* in_sizes, int n_in,
                              void* d_out, int out_size, void* d_ws, size_t ws_size,
                              hipStream_t stream) {
    const float* x    = (const float*)d_in[0];
    const float* wq   = (const float*)d_in[1];
    const float* wk   = (const float*)d_in[2];
    const float* wv   = (const float*)d_in[3];
    const float* wo   = (const float*)d_in[4];
    const float* gain = (const float*)d_in[5];
    float* out = (float*)d_out;

    char* ws = (char*)d_ws;
    unsigned short* qkv    = (unsigned short*)(ws);                              // 6 MB: 4096x768
    unsigned short* vt     = (unsigned short*)(ws + (size_t)6  * 1024 * 1024);   // 2 MB: 256x4096
    unsigned short* aout   = (unsigned short*)(ws + (size_t)8  * 1024 * 1024);   // 4 MB: 4096x512
    unsigned short* xb     = (unsigned short*)(ws + (size_t)12 * 1024 * 1024);   // 4 MB: 4096x512
    unsigned short* wqkv_b = (unsigned short*)(ws + (size_t)16 * 1024 * 1024);   // 1 MB: 1024x512
    unsigned short* wo_b   = (unsigned short*)(ws + (size_t)17 * 1024 * 1024);   // 0.5 MB
    float* cosT            = (float*)(ws + (size_t)18 * 1024 * 1024);
    float* sinT            = cosT + (size_t)S_ * (HD_ / 2);

    convert_pack_kernel<<<3072, 256, 0, stream>>>(x, wq, wk, wv, wo, xb, wqkv_b, wo_b,
                                                  cosT, sinT);
    // QK projection + fused RoPE/RMSNorm: [4096x512] @ [768x512]^T -> qkv (stride 768)
    gemm_mfma<2, unsigned short><<<dim3(6, 32), 256, 0, stream>>>(
        xb, wqkv_b, qkv, 512, 768, cosT, sinT, gain);
    // V^T projection: [256x512](wv) @ [4096x512](x)^T -> vt[256][4096]
    gemm_mfma<1, unsigned short><<<dim3(32, 2), 256, 0, stream>>>(
        wqkv_b + 768 * 512, xb, vt, 512, 4096, nullptr, nullptr, nullptr);
    attn_mfma<<<16 * (S_ / 64), 256, 0, stream>>>(qkv, vt, aout);
    gemm_mfma<0, float><<<dim3(4, 32), 256, 0, stream>>>(
        aout, wo_b, out, 512, 512, nullptr, nullptr, nullptr);
}

// Round 7
// 68.229 us; speedup vs baseline: 19.2579x; 1.1602x over previous
//
#include <hip/hip_runtime.h>
#include <math.h>

#define B_ 2
#define S_ 2048
#define D_ 512
#define H_ 8
#define KV_ 4
#define HD_ 64
// qkv row (bf16, stride 768): [q(512) | k(256)] ; V transposed in vt[256][4096]

typedef __attribute__((ext_vector_type(8))) short bf16x8;
typedef __attribute__((ext_vector_type(4))) short bf16x4;
typedef __attribute__((ext_vector_type(4))) float f32x4;
typedef __attribute__((ext_vector_type(16))) float f32x16;
typedef __attribute__((ext_vector_type(4))) unsigned u32x4;

static __device__ __forceinline__ unsigned short f2bf(float f) {
    union { float f; unsigned u; } v; v.f = f;
    unsigned r = v.u + 0x7FFFu + ((v.u >> 16) & 1);
    return (unsigned short)(r >> 16);
}

// ---------------- fp32 -> bf16 pack (x ; wq|wk|wv fused ; wo) + RoPE tables ----------------
__global__ __launch_bounds__(256) void convert_pack_kernel(
    const float* __restrict__ x, const float* __restrict__ wq, const float* __restrict__ wk,
    const float* __restrict__ wv, const float* __restrict__ wo,
    unsigned short* __restrict__ xb, unsigned short* __restrict__ wqkv_b,
    unsigned short* __restrict__ wo_b, float* __restrict__ cosT, float* __restrict__ sinT) {
    if (blockIdx.x >= 2816) {
        int idx = (blockIdx.x - 2816) * 256 + threadIdx.x;   // [0, 65536)
        int s = idx >> 5;
        int i = idx & 31;
        float invf = 1.0f / powf(10000.0f, (float)(2 * i) / (float)HD_);
        double a = (double)((float)s * invf);
        cosT[idx] = (float)cos(a);
        sinT[idx] = (float)sin(a);
        return;
    }
    int i4 = blockIdx.x * blockDim.x + threadIdx.x;
    int e = i4 * 4;
    const float* src;
    unsigned short* dst;
    if (e < 2097152)      { src = x + e;               dst = xb + e; }
    else if (e < 2359296) { src = wq + (e - 2097152);  dst = wqkv_b + (e - 2097152); }
    else if (e < 2490368) { src = wk + (e - 2359296);  dst = wqkv_b + (e - 2097152); }
    else if (e < 2621440) { src = wv + (e - 2490368);  dst = wqkv_b + (e - 2097152); }
    else                  { src = wo + (e - 2621440);  dst = wo_b + (e - 2621440); }
    float4 v = *(const float4*)src;
    bf16x4 o;
    o[0] = (short)f2bf(v.x); o[1] = (short)f2bf(v.y);
    o[2] = (short)f2bf(v.z); o[3] = (short)f2bf(v.w);
    *(bf16x4*)dst = o;
}

// ---------------- bf16 MFMA GEMM body (128x128 tile, BK=32, gload_lds staging) ----------------
// EPI: 0 = fp32 store, 1 = bf16 store, 2 = bf16 store with fused RoPE + RMSNorm (+gain on q)
template <int EPI, typename OutT>
static __device__ __forceinline__ void gemm_body(
    const unsigned short* __restrict__ A, const unsigned short* __restrict__ Bw,
    OutT* __restrict__ Y, int K, int ldy, int bn, int bm,
    unsigned short* As, unsigned short* Bs,
    const float* __restrict__ cosT, const float* __restrict__ sinT,
    const float* __restrict__ gainp) {
    const int t = threadIdx.x;
    const int w = t >> 6, l = t & 63;
    const int g = l >> 4, c = l & 15;
    const int wr = w >> 1, wc = w & 1;
    f32x4 acc[4][4] = {};
    const int lrow = l >> 2;
    const int lcol = (l & 3) * 8;
    for (int k0 = 0; k0 < K; k0 += 32) {
#pragma unroll
        for (int r = 0; r < 2; ++r) {
            int ci = w * 2 + r;
            const unsigned short* ga = A + (size_t)(bm + ci * 16 + lrow) * K + k0 + lcol;
            __builtin_amdgcn_global_load_lds(
                (const __attribute__((address_space(1))) void*)ga,
                (__attribute__((address_space(3))) void*)(As + ci * 512), 16, 0, 0);
            const unsigned short* gb = Bw + (size_t)(bn + ci * 16 + lrow) * K + k0 + lcol;
            __builtin_amdgcn_global_load_lds(
                (const __attribute__((address_space(1))) void*)gb,
                (__attribute__((address_space(3))) void*)(Bs + ci * 512), 16, 0, 0);
        }
        __syncthreads();
        bf16x8 av[4], bv[4];
#pragma unroll
        for (int i = 0; i < 4; ++i)
            av[i] = *(const bf16x8*)(As + (wr * 64 + i * 16 + c) * 32 + g * 8);
#pragma unroll
        for (int j = 0; j < 4; ++j)
            bv[j] = *(const bf16x8*)(Bs + (wc * 64 + j * 16 + c) * 32 + g * 8);
#pragma unroll
        for (int i = 0; i < 4; ++i)
#pragma unroll
            for (int j = 0; j < 4; ++j)
                acc[i][j] = __builtin_amdgcn_mfma_f32_16x16x32_bf16(av[i], bv[j], acc[i][j], 0, 0, 0);
        __syncthreads();
    }
    if constexpr (EPI == 2) {
        const float gv = *gainp;
        const float hscale = ((bn + wc * 64) < 512) ? gv : 1.0f;
#pragma unroll
        for (int i = 0; i < 4; ++i) {
#pragma unroll
            for (int r = 0; r < 4; ++r) {
                int row = bm + wr * 64 + i * 16 + g * 4 + r;
                int s = row & (S_ - 1);
                float c0 = cosT[s * 32 + c],      s0 = sinT[s * 32 + c];
                float c1 = cosT[s * 32 + c + 16], s1 = sinT[s * 32 + c + 16];
                float x1a = acc[i][0][r], x1b = acc[i][1][r];
                float x2a = acc[i][2][r], x2b = acc[i][3][r];
                float y1a = x1a * c0 + x2a * s0, y2a = x2a * c0 - x1a * s0;
                float y1b = x1b * c1 + x2b * s1, y2b = x2b * c1 - x1b * s1;
                float ss = y1a * y1a + y2a * y2a + y1b * y1b + y2b * y2b;
                ss += __shfl_xor(ss, 1, 64);
                ss += __shfl_xor(ss, 2, 64);
                ss += __shfl_xor(ss, 4, 64);
                ss += __shfl_xor(ss, 8, 64);
                float sc = rsqrtf(ss * (1.0f / 64.0f) + 1e-6f) * hscale;
                unsigned short* yr = (unsigned short*)Y + (size_t)row * ldy + bn + wc * 64 + c;
                yr[0]  = f2bf(y1a * sc);
                yr[16] = f2bf(y1b * sc);
                yr[32] = f2bf(y2a * sc);
                yr[48] = f2bf(y2b * sc);
            }
        }
    } else {
#pragma unroll
        for (int i = 0; i < 4; ++i)
#pragma unroll
            for (int j = 0; j < 4; ++j)
#pragma unroll
                for (int r = 0; r < 4; ++r) {
                    int row = bm + wr * 64 + i * 16 + g * 4 + r;
                    int col = bn + wc * 64 + j * 16 + c;
                    float v = acc[i][j][r];
                    if constexpr (EPI == 1)
                        Y[(size_t)row * ldy + col] = (OutT)f2bf(v);
                    else
                        Y[(size_t)row * ldy + col] = v;
                }
    }
}

// ---- fused projections: blocks [0,192) = QK-proj (EPI2) ; [192,256) = V^T-proj (EPI1) ----
__global__ __launch_bounds__(256) void gemm_proj_fused(
    const unsigned short* __restrict__ xb, const unsigned short* __restrict__ wqkv_b,
    unsigned short* __restrict__ qkv, unsigned short* __restrict__ vt,
    const float* __restrict__ cosT, const float* __restrict__ sinT,
    const float* __restrict__ gainp) {
    __shared__ unsigned short As[128 * 32];
    __shared__ unsigned short Bs[128 * 32];
    int bid = blockIdx.x;
    if (bid < 192) {
        int bx = bid % 6, by = bid / 6;
        gemm_body<2, unsigned short>(xb, wqkv_b, qkv, 512, 768, bx * 128, by * 128,
                                     As, Bs, cosT, sinT, gainp);
    } else {
        int b2 = bid - 192;
        int bx = b2 & 31, by = b2 >> 5;
        gemm_body<1, unsigned short>(wqkv_b + 768 * 512, xb, vt, 512, 4096, bx * 128, by * 128,
                                     As, Bs, nullptr, nullptr, nullptr);
    }
}

__global__ __launch_bounds__(256) void gemm_out(
    const unsigned short* __restrict__ A, const unsigned short* __restrict__ Bw,
    float* __restrict__ Y) {
    __shared__ unsigned short As[128 * 32];
    __shared__ unsigned short Bs[128 * 32];
    gemm_body<0, float>(A, Bw, Y, 512, 512, blockIdx.x % 4 * 128, blockIdx.x / 4 * 128,
                        As, Bs, nullptr, nullptr, nullptr);
}

// ---------------- MFMA flash attention v4: key-split partials + backfill ----------------
// Work item = (bh, qt, part): part covers K-tiles [8p, min(8p+8, qt+1)).
// slots per qt = (qt>>3)+1 ; total slots = 80 ; grid = 80*16 = 1280 blocks, qt descending.
// Fixed-shift softmax => partials combine by plain sums (no max alignment).
#define SWZF(row) ((((row) + ((row) >> 3)) & 7) << 4)

__global__ __launch_bounds__(256, 3) void attn_mfma(const unsigned short* __restrict__ qkv,
                                                    const unsigned short* __restrict__ vt,
                                                    unsigned short* __restrict__ aout,
                                                    float* __restrict__ pO,
                                                    float* __restrict__ pL) {
    __shared__ alignas(128) char smem[32768];
    // [0,16K): Ks dbuf ; [16K,32K): Vts dbuf ; epilogue overlay: Os f32[64][64] at 0, Ls at +16K

    const int slot = blockIdx.x >> 4;
    const int bh = blockIdx.x & 15;
    int qt = 31, acc = 0;
    while (acc + (qt >> 3) + 1 <= slot) { acc += (qt >> 3) + 1; --qt; }
    const int part = slot - acc;
    const int np = (qt >> 3) + 1;
    const int kt0 = part * 8;
    const int kt1 = min(kt0 + 8, qt + 1);   // exclusive
    const int hh = bh & 7;
    const int b = bh >> 3;
    const int kvh = hh >> 1;

    const int t = threadIdx.x;
    const int w = t >> 6;
    const int l = t & 63;
    const int wq = w >> 1;   // q-half
    const int wk = w & 1;    // key-half
    const int hl = l >> 5;
    const int l31 = l & 31;

    const int row0 = t >> 3;
    const int row1 = (256 + t) >> 3;
    const int seg = l & 7;
    const int off0 = (seg * 16) ^ SWZF(row0);
    const int off1 = (seg * 16) ^ SWZF(row1);
    const int cb0 = w * 1024;
    const int cb1 = 4096 + w * 1024;

    // ---- Q B-frags straight from global (L2-resident) ----
    bf16x8 qf[4];
    {
        const unsigned short* qrow =
            qkv + (size_t)(b * S_ + qt * 64 + wq * 32 + l31) * 768 + hh * 64 + hl * 8;
#pragma unroll
        for (int kd = 0; kd < 4; ++kd)
            qf[kd] = *(const bf16x8*)(qrow + kd * 16);
    }

    const char* kb = (const char*)qkv + ((size_t)(b * S_)) * 1536 + 1024 + kvh * 128;
    const char* vb = (const char*)vt + ((size_t)(kvh * 64)) * 8192 + (size_t)(b * S_) * 2;

#define STAGE(kt_, bufi_)                                                                        \
    do {                                                                                         \
        const char* ks_ = kb + (size_t)(kt_) * 64 * 1536;                                        \
        const char* vs_ = vb + (size_t)(kt_) * 128;                                              \
        char* kd_ = smem + (bufi_)*8192;                                                         \
        char* vd_ = smem + 16384 + (bufi_)*8192;                                                 \
        __builtin_amdgcn_global_load_lds(                                                        \
            (const __attribute__((address_space(1))) void*)(ks_ + (size_t)row0 * 1536 + off0),   \
            (__attribute__((address_space(3))) void*)(kd_ + cb0), 16, 0, 0);                     \
        __builtin_amdgcn_global_load_lds(                                                        \
            (const __attribute__((address_space(1))) void*)(ks_ + (size_t)row1 * 1536 + off1),   \
            (__attribute__((address_space(3))) void*)(kd_ + cb1), 16, 0, 0);                     \
        __builtin_amdgcn_global_load_lds(                                                        \
            (const __attribute__((address_space(1))) void*)(vs_ + (size_t)row0 * 8192 + off0),   \
            (__attribute__((address_space(3))) void*)(vd_ + cb0), 16, 0, 0);                     \
        __builtin_amdgcn_global_load_lds(                                                        \
            (const __attribute__((address_space(1))) void*)(vs_ + (size_t)row1 * 8192 + off1),   \
            (__attribute__((address_space(3))) void*)(vd_ + cb1), 16, 0, 0);                     \
    } while (0)

    STAGE(kt0, 0);
    __syncthreads();

    float l_part = 0.0f;
    f32x16 o_acc[2] = {};
    const float LS = 0.125f * 1.4426950408889634f;
    const float SH = 6.0f * 1.4426950408889634f;

    int buf = 0;
    for (int kt = kt0; kt < kt1; ++kt) {
        if (kt + 1 < kt1) STAGE(kt + 1, buf ^ 1);
        const char* KsB = smem + buf * 8192;
        const char* VtB = smem + 16384 + buf * 8192;
        const bool diag = (kt == qt);

        if (!(diag && wk > wq)) {
            f32x16 s_acc = {};
            {
                int arow = wk * 32 + l31;
                int af = SWZF(arow);
                __builtin_amdgcn_s_setprio(1);
#pragma unroll
                for (int kd = 0; kd < 4; ++kd) {
                    bf16x8 afr = *(const bf16x8*)(KsB + arow * 128 + ((kd * 32 + hl * 16) ^ af));
                    s_acc = __builtin_amdgcn_mfma_f32_32x32x16_bf16(afr, qf[kd], s_acc, 0, 0, 0);
                }
                __builtin_amdgcn_s_setprio(0);
            }
            bf16x8 vf[2][2];
#pragma unroll
            for (int nd = 0; nd < 2; ++nd) {
                int vr = nd * 32 + l31;
                int fv = SWZF(vr);
#pragma unroll
                for (int m = 0; m < 2; ++m)
                    vf[nd][m] = *(const bf16x8*)(VtB + vr * 128 + ((wk * 64 + m * 32 + hl * 16) ^ fv));
            }
            float p[16];
            if (diag && wk == wq) {
#pragma unroll
                for (int idx = 0; idx < 16; ++idx) {
                    int keyin = 4 * hl + 8 * (idx >> 2) + (idx & 3);
                    float e = exp2f(s_acc[idx] * LS - SH);
                    p[idx] = (keyin <= l31) ? e : 0.0f;
                }
            } else {
#pragma unroll
                for (int idx = 0; idx < 16; ++idx)
                    p[idx] = exp2f(s_acc[idx] * LS - SH);
            }
#pragma unroll
            for (int idx = 0; idx < 16; ++idx) l_part += p[idx];
            unsigned pw[8];
#pragma unroll
            for (int s = 0; s < 4; ++s)
#pragma unroll
                for (int j = 0; j < 2; ++j)
                    asm("v_cvt_pk_bf16_f32 %0, %1, %2"
                        : "=v"(pw[s * 2 + j])
                        : "v"(p[4 * s + 2 * j]), "v"(p[4 * s + 2 * j + 1]));
#pragma unroll
            for (int m = 0; m < 2; ++m) {
                asm volatile("v_permlane32_swap_b32 %0, %1" : "+v"(pw[4 * m + 0]), "+v"(pw[4 * m + 2]));
                asm volatile("v_permlane32_swap_b32 %0, %1" : "+v"(pw[4 * m + 1]), "+v"(pw[4 * m + 3]));
            }
            __builtin_amdgcn_s_setprio(1);
#pragma unroll
            for (int m = 0; m < 2; ++m) {
                u32x4 fu = {pw[4 * m + 0], pw[4 * m + 1], pw[4 * m + 2], pw[4 * m + 3]};
                bf16x8 pfr = *(bf16x8*)&fu;
#pragma unroll
                for (int nd = 0; nd < 2; ++nd)
                    o_acc[nd] = __builtin_amdgcn_mfma_f32_32x32x16_bf16(pfr, vf[nd][m], o_acc[nd], 0, 0, 0);
            }
            __builtin_amdgcn_s_setprio(0);
        }
        __syncthreads();
        buf ^= 1;
    }
#undef STAGE

    // ---- epilogue: cross-wk reduce via LDS overlay ----
    float* Os = (float*)smem;
    float* Ls = (float*)(smem + 16384);
    float lsum = l_part + __shfl_xor(l_part, 32, 64);
    if (hl == 0) Ls[wk * 64 + wq * 32 + l31] = lsum;
    if (wk == 0) {
#pragma unroll
        for (int nd = 0; nd < 2; ++nd)
#pragma unroll
            for (int reg = 0; reg < 16; ++reg) {
                int qrow = 4 * hl + 8 * (reg >> 2) + (reg & 3);
                Os[(wq * 32 + qrow) * 64 + nd * 32 + l31] = o_acc[nd][reg];
            }
    }
    __syncthreads();
    if (wk == 1) {
        if (np == 1) {
            // direct write (qt <= 7): normalize here
            unsigned short* ob = aout + ((size_t)(b * S_ + qt * 64 + wq * 32)) * 512 + hh * 64;
#pragma unroll
            for (int reg = 0; reg < 16; ++reg) {
                int qrow = 4 * hl + 8 * (reg >> 2) + (reg & 3);
                float ltot = Ls[wq * 32 + qrow] + Ls[64 + wq * 32 + qrow];
                float inv = __builtin_amdgcn_rcpf(ltot);
#pragma unroll
                for (int nd = 0; nd < 2; ++nd) {
                    float val = (o_acc[nd][reg] + Os[(wq * 32 + qrow) * 64 + nd * 32 + l31]) * inv;
                    ob[(size_t)qrow * 512 + nd * 32 + l31] = f2bf(val);
                }
            }
        } else {
            // partial write (f32 O + l), combined later
            float* po = pO + (size_t)blockIdx.x * 4096;
            float* pl = pL + (size_t)blockIdx.x * 64;
#pragma unroll
            for (int reg = 0; reg < 16; ++reg) {
                int qrow = 4 * hl + 8 * (reg >> 2) + (reg & 3);
                float ltot = Ls[wq * 32 + qrow] + Ls[64 + wq * 32 + qrow];
                if (l31 == 0) pl[wq * 32 + qrow] = ltot;
#pragma unroll
                for (int nd = 0; nd < 2; ++nd)
                    po[(wq * 32 + qrow) * 64 + nd * 32 + l31] =
                        o_acc[nd][reg] + Os[(wq * 32 + qrow) * 64 + nd * 32 + l31];
            }
        }
    }
}

// ---------------- combine partials for qt >= 8 (np >= 2): O = sum, l = sum, normalize ----------------
__global__ __launch_bounds__(256) void combine_kernel(const float* __restrict__ pO,
                                                      const float* __restrict__ pL,
                                                      unsigned short* __restrict__ aout) {
    const int cid = blockIdx.x;          // 384 = 24 qt values x 16 bh
    const int bh = cid & 15;
    const int qt = 31 - (cid >> 4);      // qt in [8, 31]
    int qq = 31, acc = 0;
    while (qq > qt) { acc += (qq >> 3) + 1; --qq; }
    const int np = (qt >> 3) + 1;
    const int base = acc * 16 + bh;      // partial pid = base + p*16
    const int t = threadIdx.x;
    const int row = t >> 2;
    const int c0 = (t & 3) * 16;
    float l = 0.0f;
    float o[16] = {};
    for (int p = 0; p < np; ++p) {
        const int pid = base + p * 16;
        l += pL[(size_t)pid * 64 + row];
        const float* po = pO + (size_t)pid * 4096 + row * 64 + c0;
#pragma unroll
        for (int j4 = 0; j4 < 4; ++j4) {
            float4 v = *(const float4*)(po + j4 * 4);
            o[j4 * 4 + 0] += v.x; o[j4 * 4 + 1] += v.y;
            o[j4 * 4 + 2] += v.z; o[j4 * 4 + 3] += v.w;
        }
    }
    float inv = __builtin_amdgcn_rcpf(l);
    const int b = bh >> 3, hh = bh & 7;
    unsigned short* ob = aout + (size_t)(b * S_ + qt * 64 + row) * 512 + hh * 64 + c0;
    bf16x4 pk[4];
#pragma unroll
    for (int j4 = 0; j4 < 4; ++j4) {
        pk[j4][0] = (short)f2bf(o[j4 * 4 + 0] * inv);
        pk[j4][1] = (short)f2bf(o[j4 * 4 + 1] * inv);
        pk[j4][2] = (short)f2bf(o[j4 * 4 + 2] * inv);
        pk[j4][3] = (short)f2bf(o[j4 * 4 + 3] * inv);
        *(bf16x4*)(ob + j4 * 4) = pk[j4];
    }
}

extern "C" void kernel_launch(void* const* d_in, const int* in_sizes, int n_in,
                              void* d_out, int out_size, void* d_ws, size_t ws_size,
                              hipStream_t stream) {
    const float* x    = (const float*)d_in[0];
    const float* wq   = (const float*)d_in[1];
    const float* wk   = (const float*)d_in[2];
    const float* wv   = (const float*)d_in[3];
    const float* wo   = (const float*)d_in[4];
    const float* gain = (const float*)d_in[5];
    float* out = (float*)d_out;

    char* ws = (char*)d_ws;
    unsigned short* qkv    = (unsigned short*)(ws);                              // 6 MB: 4096x768
    unsigned short* vt     = (unsigned short*)(ws + (size_t)6  * 1024 * 1024);   // 2 MB: 256x4096
    unsigned short* aout   = (unsigned short*)(ws + (size_t)8  * 1024 * 1024);   // 4 MB: 4096x512
    unsigned short* xb     = (unsigned short*)(ws + (size_t)12 * 1024 * 1024);   // 4 MB
    unsigned short* wqkv_b = (unsigned short*)(ws + (size_t)16 * 1024 * 1024);   // 1 MB
    unsigned short* wo_b   = (unsigned short*)(ws + (size_t)17 * 1024 * 1024);   // 0.5 MB
    float* cosT            = (float*)(ws + (size_t)18 * 1024 * 1024);
    float* sinT            = cosT + (size_t)S_ * (HD_ / 2);
    float* pO              = (float*)(ws + (size_t)32 * 1024 * 1024);            // 1280 x 4096 f32
    float* pL              = pO + (size_t)1280 * 4096;                           // 1280 x 64 f32

    convert_pack_kernel<<<3072, 256, 0, stream>>>(x, wq, wk, wv, wo, xb, wqkv_b, wo_b,
                                                  cosT, sinT);
    gemm_proj_fused<<<256, 256, 0, stream>>>(xb, wqkv_b, qkv, vt, cosT, sinT, gain);
    attn_mfma<<<1280, 256, 0, stream>>>(qkv, vt, aout, pO, pL);
    combine_kernel<<<384, 256, 0, stream>>>(pO, pL, aout);
    gemm_out<<<128, 256, 0, stream>>>(aout, wo_b, out);
}